// Round 1
// baseline (1042.096 us; speedup 1.0000x reference)
//
#include <hip/hip_runtime.h>

#define NF 128
#define NT 256
#define TROWS 64
#define NLAT 21
#define NBATCH 2048
#define LEN_T 51
#define NSHIFT 50
#define AUTO_ROWS (NBATCH*LEN_T)   // 104448
#define PRED_ROWS (NBATCH*NSHIFT)  // 102400

__device__ __forceinline__ void fma4(float4& a, float s, float4 w) {
  a.x = fmaf(s, w.x, a.x);
  a.y = fmaf(s, w.y, a.y);
  a.z = fmaf(s, w.z, a.z);
  a.w = fmaf(s, w.w, a.w);
}

// 64x128 @ 128x128 tile GEMM.
// Layout: 4 waves; wave owns rows [wid*16, wid*16+16); half-wave owns 8 rows;
// lane owns 4 consecutive output cols (cg = lane&31 -> cols 4cg..4cg+3).
// W staged from global into 32-row LDS chunks (16KB).
__device__ __forceinline__ void gemm128(const float* hin, float* wbuf,
                                        const float* __restrict__ gW,
                                        float4 acc[8], int tid, int row0, int cg) {
#pragma unroll
  for (int r = 0; r < 8; ++r) acc[r] = make_float4(0.f, 0.f, 0.f, 0.f);
#pragma unroll 1
  for (int kc = 0; kc < 4; ++kc) {
    __syncthreads();  // all waves done with previous wbuf contents
    {
      const float4* src = (const float4*)(gW + kc * 32 * NF);
      float4* dst = (float4*)wbuf;
#pragma unroll
      for (int i = 0; i < 4; ++i) dst[tid + i * NT] = src[tid + i * NT];
    }
    __syncthreads();
#pragma unroll 2
    for (int k4 = 0; k4 < 8; ++k4) {
      const float4* wrow = (const float4*)wbuf + k4 * 4 * 32 + cg;
      float4 w0 = wrow[0];
      float4 w1 = wrow[32];
      float4 w2 = wrow[64];
      float4 w3 = wrow[96];
      const float* hp = hin + row0 * NF + kc * 32 + k4 * 4;
#pragma unroll
      for (int r = 0; r < 8; ++r) {
        float4 hv = *(const float4*)(hp + r * NF);  // broadcast (2 addrs/wave)
        fma4(acc[r], hv.x, w0);
        fma4(acc[r], hv.y, w1);
        fma4(acc[r], hv.z, w2);
        fma4(acc[r], hv.w, w3);
      }
    }
  }
}

// M = ienc_W (128x21) @ idec_W (21x128)
__global__ void k_mmul(const float* __restrict__ ienc, const float* __restrict__ idec,
                       float* __restrict__ M) {
  int idx = blockIdx.x * 256 + threadIdx.x;  // 16384 threads
  int i = idx >> 7, j = idx & 127;
  float s = 0.f;
#pragma unroll
  for (int k = 0; k < NLAT; ++k) s = fmaf(ienc[i * NLAT + k], idec[k * NF + j], s);
  M[idx] = s;
}

__global__ __launch_bounds__(NT, 3)
void k_main(const float* __restrict__ gin,
            const float* __restrict__ encW, const float* __restrict__ encB,
            const float* __restrict__ encWo, const float* __restrict__ encBo,
            const float* __restrict__ decW, const float* __restrict__ decB,
            const float* __restrict__ decWo, const float* __restrict__ decBo,
            const float* __restrict__ iencW, const float* __restrict__ Mmat,
            float* __restrict__ out1, float* __restrict__ out2,
            float* __restrict__ z0) {
  __shared__ float hbuf[TROWS * NF];   // 32 KB
  __shared__ float wbuf[32 * NF];      // 16 KB
  const int tid = threadIdx.x;
  const int lane = tid & 63, wid = tid >> 6;
  const int cg = lane & 31;
  const int row0 = wid * 16 + (lane >> 5) * 8;
  const int grow0 = blockIdx.x * TROWS;

  // stage input tile
  {
    const float4* src = (const float4*)gin + grow0 * (NF / 4);
    float4* dst = (float4*)hbuf;
#pragma unroll
    for (int i = 0; i < 8; ++i) dst[tid + i * NT] = src[tid + i * NT];
  }
  __syncthreads();
  float4 res[8], acc[8];
#pragma unroll
  for (int r = 0; r < 8; ++r) res[r] = ((const float4*)hbuf)[(row0 + r) * 32 + cg];

  // ---- encoder resblock ----
#pragma unroll 1
  for (int l = 0; l < 4; ++l) {
    gemm128(hbuf, wbuf, encW + l * NF * NF, acc, tid, row0, cg);
    float4 b4 = ((const float4*)(encB + l * NF))[cg];
#pragma unroll
    for (int r = 0; r < 8; ++r) {
      float4 v = acc[r];
      v.x = fmaxf(v.x + b4.x, 0.f); v.y = fmaxf(v.y + b4.y, 0.f);
      v.z = fmaxf(v.z + b4.z, 0.f); v.w = fmaxf(v.w + b4.w, 0.f);
      ((float4*)hbuf)[(row0 + r) * 32 + cg] = v;
    }
  }
  gemm128(hbuf, wbuf, encWo, acc, tid, row0, cg);
  {
    float4 b4 = ((const float4*)encBo)[cg];
#pragma unroll
    for (int r = 0; r < 8; ++r) {
      float4 v = res[r];
      v.x += acc[r].x + b4.x; v.y += acc[r].y + b4.y;
      v.z += acc[r].z + b4.z; v.w += acc[r].w + b4.w;
      res[r] = v;                                    // res = pe (kept for pass A + restore)
      ((float4*)hbuf)[(row0 + r) * 32 + cg] = v;     // hbuf = pe
    }
  }
  __syncthreads();  // pe visible to all waves (needed for z0 rows)

  // ---- z0 = pe[t==0] @ ienc_W ----
  if (tid < NLAT) {
#pragma unroll 1
    for (int r = 0; r < TROWS; ++r) {
      int grow = grow0 + r;
      if (grow % LEN_T == 0) {
        int b = grow / LEN_T;
        float s = 0.f;
#pragma unroll 1
        for (int k = 0; k < NF; ++k) s = fmaf(hbuf[r * NF + k], iencW[k * NLAT + tid], s);
        z0[b * NLAT + tid] = s;
      }
    }
  }

  // ---- pass A: outer_auto_output = dec resblock on pe ----
#pragma unroll 1
  for (int l = 0; l < 4; ++l) {
    gemm128(hbuf, wbuf, decW + l * NF * NF, acc, tid, row0, cg);
    float4 b4 = ((const float4*)(decB + l * NF))[cg];
#pragma unroll
    for (int r = 0; r < 8; ++r) {
      float4 v = acc[r];
      v.x = fmaxf(v.x + b4.x, 0.f); v.y = fmaxf(v.y + b4.y, 0.f);
      v.z = fmaxf(v.z + b4.z, 0.f); v.w = fmaxf(v.w + b4.w, 0.f);
      ((float4*)hbuf)[(row0 + r) * 32 + cg] = v;
    }
  }
  gemm128(hbuf, wbuf, decWo, acc, tid, row0, cg);
  {
    float4 b4 = ((const float4*)decBo)[cg];
#pragma unroll
    for (int r = 0; r < 8; ++r) {
      float4 v;
      v.x = res[r].x + acc[r].x + b4.x; v.y = res[r].y + acc[r].y + b4.y;
      v.z = res[r].z + acc[r].z + b4.z; v.w = res[r].w + acc[r].w + b4.w;
      ((float4*)out2)[(grow0 + row0 + r) * 32 + cg] = v;
    }
  }

  // ---- pd = pe @ M  (M = ienc@idec precomputed; pe restored from registers) ----
#pragma unroll
  for (int r = 0; r < 8; ++r) ((float4*)hbuf)[(row0 + r) * 32 + cg] = res[r];
  gemm128(hbuf, wbuf, Mmat, acc, tid, row0, cg);
#pragma unroll
  for (int r = 0; r < 8; ++r) {
    res[r] = acc[r];                                  // res = pd
    ((float4*)hbuf)[(row0 + r) * 32 + cg] = acc[r];   // hbuf = pd
  }

  // ---- pass B: autoencoder_output = dec resblock on pd ----
#pragma unroll 1
  for (int l = 0; l < 4; ++l) {
    gemm128(hbuf, wbuf, decW + l * NF * NF, acc, tid, row0, cg);
    float4 b4 = ((const float4*)(decB + l * NF))[cg];
#pragma unroll
    for (int r = 0; r < 8; ++r) {
      float4 v = acc[r];
      v.x = fmaxf(v.x + b4.x, 0.f); v.y = fmaxf(v.y + b4.y, 0.f);
      v.z = fmaxf(v.z + b4.z, 0.f); v.w = fmaxf(v.w + b4.w, 0.f);
      ((float4*)hbuf)[(row0 + r) * 32 + cg] = v;
    }
  }
  gemm128(hbuf, wbuf, decWo, acc, tid, row0, cg);
  {
    float4 b4 = ((const float4*)decBo)[cg];
#pragma unroll
    for (int r = 0; r < 8; ++r) {
      float4 v;
      v.x = res[r].x + acc[r].x + b4.x; v.y = res[r].y + acc[r].y + b4.y;
      v.z = res[r].z + acc[r].z + b4.z; v.w = res[r].w + acc[r].w + b4.w;
      ((float4*)out1)[(grow0 + row0 + r) * 32 + cg] = v;
    }
  }
}

// 50-step latent rollout: zs[s][b][:] = z0[b] @ L^(s+1)
// 2 rows per wave; lanes 0..20 / 32..52 hold one latent feature each;
// L column kept in registers, z broadcast via shfl.
__global__ void k_rollout(const float* __restrict__ z0, const float* __restrict__ L,
                          float* __restrict__ zs) {
  const int tid = threadIdx.x;
  const int lane = tid & 63, wid = tid >> 6;
  const int sub = lane & 31, half = lane >> 5;
  const int row = blockIdx.x * 8 + wid * 2 + half;
  const bool act = sub < NLAT;
  float Lc[NLAT];
#pragma unroll
  for (int k = 0; k < NLAT; ++k) Lc[k] = act ? L[k * NLAT + sub] : 0.f;
  float z = act ? z0[row * NLAT + sub] : 0.f;
  const int base = half * 32;
#pragma unroll 1
  for (int s = 0; s < NSHIFT; ++s) {
    float zn = 0.f;
#pragma unroll
    for (int k = 0; k < NLAT; ++k) zn = fmaf(__shfl(z, base + k, 64), Lc[k], zn);
    z = zn;
    if (act) zs[(s * NBATCH + row) * NLAT + sub] = z;
  }
}

__global__ __launch_bounds__(NT, 3)
void k_pred(const float* __restrict__ zs, const float* __restrict__ idecW,
            const float* __restrict__ decW, const float* __restrict__ decB,
            const float* __restrict__ decWo, const float* __restrict__ decBo,
            float* __restrict__ out3) {
  __shared__ float hbuf[TROWS * NF];
  __shared__ float wbuf[32 * NF];
  const int tid = threadIdx.x;
  const int lane = tid & 63;
  const int cg = lane & 31;
  const int row0 = (tid >> 6) * 16 + (lane >> 5) * 8;
  const int grow0 = blockIdx.x * TROWS;

  // stage idec (21x128 = 672 f4) then the z tile (64x21 = 336 f4) into wbuf
  {
    float4* d = (float4*)wbuf;
    const float4* s1 = (const float4*)idecW;
#pragma unroll 1
    for (int i = tid; i < 672; i += NT) d[i] = s1[i];
    const float4* s2 = (const float4*)(zs + grow0 * NLAT);
#pragma unroll 1
    for (int i = tid; i < 336; i += NT) d[672 + i] = s2[i];
  }
  __syncthreads();

  float4 acc[8], res[8];
#pragma unroll
  for (int r = 0; r < 8; ++r) acc[r] = make_float4(0.f, 0.f, 0.f, 0.f);
#pragma unroll 1
  for (int k = 0; k < NLAT; ++k) {
    float4 wv = ((const float4*)wbuf)[k * 32 + cg];
#pragma unroll
    for (int r = 0; r < 8; ++r) {
      float zv = wbuf[2688 + (row0 + r) * NLAT + k];  // broadcast
      fma4(acc[r], zv, wv);
    }
  }
#pragma unroll
  for (int r = 0; r < 8; ++r) {
    res[r] = acc[r];                                  // dec_in (residual)
    ((float4*)hbuf)[(row0 + r) * 32 + cg] = acc[r];
  }

  // dec resblock
#pragma unroll 1
  for (int l = 0; l < 4; ++l) {
    gemm128(hbuf, wbuf, decW + l * NF * NF, acc, tid, row0, cg);
    float4 b4 = ((const float4*)(decB + l * NF))[cg];
#pragma unroll
    for (int r = 0; r < 8; ++r) {
      float4 v = acc[r];
      v.x = fmaxf(v.x + b4.x, 0.f); v.y = fmaxf(v.y + b4.y, 0.f);
      v.z = fmaxf(v.z + b4.z, 0.f); v.w = fmaxf(v.w + b4.w, 0.f);
      ((float4*)hbuf)[(row0 + r) * 32 + cg] = v;
    }
  }
  gemm128(hbuf, wbuf, decWo, acc, tid, row0, cg);
  {
    float4 b4 = ((const float4*)decBo)[cg];
#pragma unroll
    for (int r = 0; r < 8; ++r) {
      int grow = grow0 + row0 + r;       // = s*2048 + b
      int sh = grow >> 11;
      int b = grow & 2047;
      float4 v;
      v.x = res[r].x + acc[r].x + b4.x; v.y = res[r].y + acc[r].y + b4.y;
      v.z = res[r].z + acc[r].z + b4.z; v.w = res[r].w + acc[r].w + b4.w;
      ((float4*)out3)[(b * NSHIFT + sh) * 32 + cg] = v;   // predictions[b][s]
    }
  }
}

extern "C" void kernel_launch(void* const* d_in, const int* in_sizes, int n_in,
                              void* d_out, int out_size, void* d_ws, size_t ws_size,
                              hipStream_t stream) {
  const float* gin   = (const float*)d_in[0];
  const float* L     = (const float*)d_in[1];
  const float* iencW = (const float*)d_in[2];
  const float* idecW = (const float*)d_in[3];
  const float* encW  = (const float*)d_in[4];
  const float* encB  = (const float*)d_in[5];
  const float* encWo = (const float*)d_in[6];
  const float* encBo = (const float*)d_in[7];
  const float* decW  = (const float*)d_in[8];
  const float* decB  = (const float*)d_in[9];
  const float* decWo = (const float*)d_in[10];
  const float* decBo = (const float*)d_in[11];

  float* out1 = (float*)d_out;                       // autoencoder_output
  float* out2 = out1 + (size_t)AUTO_ROWS * NF;       // outer_auto_output
  float* out3 = out2 + (size_t)AUTO_ROWS * NF;       // predictions

  float* M  = (float*)d_ws;                          // 128*128
  float* z0 = M + NF * NF;                           // 2048*21
  float* zs = z0 + NBATCH * NLAT;                    // 50*2048*21

  hipLaunchKernelGGL(k_mmul, dim3(64), dim3(256), 0, stream, iencW, idecW, M);
  hipLaunchKernelGGL(k_main, dim3(AUTO_ROWS / TROWS), dim3(NT), 0, stream,
                     gin, encW, encB, encWo, encBo, decW, decB, decWo, decBo,
                     iencW, M, out1, out2, z0);
  hipLaunchKernelGGL(k_rollout, dim3(NBATCH / 8), dim3(NT), 0, stream, z0, L, zs);
  hipLaunchKernelGGL(k_pred, dim3(PRED_ROWS / TROWS), dim3(NT), 0, stream,
                     zs, idecW, decW, decB, decWo, decBo, out3);
}

// Round 2
// 763.317 us; speedup vs baseline: 1.3652x; 1.3652x over previous
//
#include <hip/hip_runtime.h>

#define NF 128
#define NLAT 21
#define NBATCH 2048
#define LEN_T 51
#define NSHIFT 50
#define AUTO_ROWS (NBATCH*LEN_T)   // 104448
#define PRED_ROWS (NBATCH*NSHIFT)  // 102400

typedef short bh8  __attribute__((ext_vector_type(8)));   // 8 bf16 (A/B frag, 4 VGPR)
typedef unsigned short us8 __attribute__((ext_vector_type(8)));
typedef float f32x4  __attribute__((ext_vector_type(4)));
typedef float f32x16 __attribute__((ext_vector_type(16))); // 32x32 accumulator

#define MFMA32(A,B,C) __builtin_amdgcn_mfma_f32_32x32x16_bf16(A,B,C,0,0,0)

// ---------- helpers ----------
__device__ __forceinline__ float bf2f(short s){
  unsigned u = ((unsigned)(unsigned short)s) << 16;
  return __builtin_bit_cast(float, u);
}
__device__ __forceinline__ void split1(float v, unsigned short& hi, unsigned short& lo){
  unsigned u  = __builtin_bit_cast(unsigned, v);
  unsigned h  = (u + 0x7FFFu + ((u>>16)&1u)) >> 16;          // RNE bf16
  float    l  = v - __builtin_bit_cast(float, h<<16);        // exact residual
  unsigned ul = __builtin_bit_cast(unsigned, l);
  unsigned lw = (ul + 0x7FFFu + ((ul>>16)&1u)) >> 16;        // RNE bf16 of residual
  hi = (unsigned short)h; lo = (unsigned short)lw;
}
__device__ __forceinline__ void split8(const float v[8], bh8& hi, bh8& lo){
#pragma unroll
  for(int i=0;i<8;++i){ unsigned short a,b; split1(v[i],a,b); hi[i]=(short)a; lo[i]=(short)b; }
}

// ---------- tiny prep kernels (run every call; ~µs) ----------
// M = ienc_W (128x21) @ idec_W (21x128), f32
__global__ void k_mmul(const float* __restrict__ ienc, const float* __restrict__ idec,
                       float* __restrict__ M){
  int idx = blockIdx.x*256 + threadIdx.x;      // 16384
  int i = idx>>7, j = idx&127;
  float s = 0.f;
#pragma unroll
  for(int k=0;k<NLAT;++k) s = fmaf(ienc[i*NLAT+k], idec[k*NF+j], s);
  M[idx] = s;
}

// Build swizzled split-bf16 A-operand planes for 12 matrices.
// mats: 0-3 enc_W[l], 4 enc_Wo, 5-8 dec_W[l], 9 dec_Wo, 10 M, 11 idec^T (K=21 pad)
// Frag(s,mt): lane l elem i = W[s*16 + kappa(h,i)][mt*32 + (l&31)], kappa=4h+(i&3)+8(i>>2)
// layout (ushort units): mat*32768 + [hi:0 | lo:16384] + (s*4+mt)*512 + lane*8
__global__ void k_prep(const float* __restrict__ encW, const float* __restrict__ encWo,
                       const float* __restrict__ decW, const float* __restrict__ decWo,
                       const float* __restrict__ M,    const float* __restrict__ idec,
                       unsigned short* __restrict__ swz){
  int id  = blockIdx.x*256 + threadIdx.x;  // 12 * 2048
  int mat = id >> 11;
  int rem = id & 2047;
  int f   = rem >> 6, l = rem & 63;
  int s   = f >> 2,  mt = f & 3;
  int hl  = l >> 5,  c  = l & 31;
  const float* src;
  if(mat<4)       src = encW + mat*16384;
  else if(mat==4) src = encWo;
  else if(mat<9)  src = decW + (mat-5)*16384;
  else if(mat==9) src = decWo;
  else if(mat==10)src = M;
  else            src = idec;
  us8 hi8, lo8;
#pragma unroll
  for(int i=0;i<8;++i){
    int k = s*16 + 4*hl + (i&3) + 8*(i>>2);
    float v;
    if(mat==11) v = (k<NLAT) ? src[k*NF + mt*32 + c] : 0.f;
    else        v = src[k*NF + mt*32 + c];
    unsigned short a,b; split1(v,a,b); hi8[i]=a; lo8[i]=b;
  }
  size_t base = (size_t)mat*32768 + (size_t)f*512 + (size_t)l*8;
  *(us8*)(swz + base)         = hi8;
  *(us8*)(swz + base + 16384) = lo8;
}

// ---------- core: one 128->128 layer, all-register ----------
// acc[mt] (mt=0..3 out-feat tiles of 32) over 8 K-windows of 16; 96 MFMA.
__device__ __forceinline__ void run_layer(const unsigned short* __restrict__ sw,
    const bh8 hi[8], const bh8 lo[8], f32x16 acc[4], int lane){
  const bh8* W = (const bh8*)sw;
  f32x16 z;
#pragma unroll
  for(int r=0;r<16;++r) z[r]=0.f;
#pragma unroll
  for(int mt=0;mt<4;++mt) acc[mt]=z;
#pragma unroll
  for(int s=0;s<8;++s){
    bh8 bh=hi[s], bl=lo[s];
#pragma unroll
    for(int mt=0;mt<4;++mt){
      bh8 whi = W[(s*4+mt)*64 + lane];
      bh8 wlo = W[2048 + (s*4+mt)*64 + lane];
      acc[mt]=MFMA32(whi,bh,acc[mt]);
      acc[mt]=MFMA32(whi,bl,acc[mt]);
      acc[mt]=MFMA32(wlo,bh,acc[mt]);
    }
  }
}

// epilogue: acc -> (bias, residual, relu) -> split-bf16 frags for next layer.
// D reg r of tile mt: feat = mt*32 + (r&3) + 8*(r>>2) + 4*hl; frag(s=2mt+p) elem i <-> r = p*8+4*(i>>2)+(i&3)
template<bool RELU,bool BIAS,bool RES>
__device__ __forceinline__ void epi(f32x16 acc[4], const float* __restrict__ bias,
    const bh8 rhi[8], const bh8 rlo[8], bh8 ohi[8], bh8 olo[8], int hl){
#pragma unroll
  for(int mt=0;mt<4;++mt){
    f32x16 a = acc[mt];
    if(BIAS){
#pragma unroll
      for(int q=0;q<4;++q){
        f32x4 b = *(const f32x4*)(bias + mt*32 + q*8 + hl*4);
#pragma unroll
        for(int j=0;j<4;++j) a[q*4+j]+=b[j];
      }
    }
    if(RES){
#pragma unroll
      for(int r=0;r<16;++r){
        int s=mt*2+(r>>3), i=((r>>2)&1)*4+(r&3);
        a[r] += bf2f(rhi[s][i]) + bf2f(rlo[s][i]);
      }
    }
    if(RELU){
#pragma unroll
      for(int r=0;r<16;++r) a[r]=fmaxf(a[r],0.f);
    }
#pragma unroll
    for(int p=0;p<2;++p){
      float v[8];
#pragma unroll
      for(int i=0;i<8;++i) v[i]=a[p*8 + (i>>2)*4 + (i&3)];
      split8(v, ohi[mt*2+p], olo[mt*2+p]);
    }
  }
}

// dec resblock body: 4 relu layers + linear Wo (residual added by caller)
__device__ __forceinline__ void dec_layers(const unsigned short* __restrict__ swz,
    const float* __restrict__ decB,
    const bh8 phi[8], const bh8 plo[8], bh8 hhi[8], bh8 hlo[8],
    f32x16 acc[4], int lane, int hl){
  run_layer(swz + (size_t)5*32768, phi, plo, acc, lane);
  epi<true,true,false>(acc, decB, nullptr, nullptr, hhi, hlo, hl);
#pragma unroll 1
  for(int l=1;l<4;++l){
    run_layer(swz + (size_t)(5+l)*32768, hhi, hlo, acc, lane);
    epi<true,true,false>(acc, decB + l*NF, nullptr, nullptr, hhi, hlo, hl);
  }
  run_layer(swz + (size_t)9*32768, hhi, hlo, acc, lane);
}

// final: acc + bias_o + recon(res frags) -> LDS coalesce -> global (opt. pred remap)
__device__ __forceinline__ void final_stage(float* st, float* __restrict__ gout,
    const f32x16 acc[4], const float* __restrict__ bo,
    const bh8 rhi[8], const bh8 rlo[8],
    int tid, int wid, int c31, int hl, int grow0, bool predmap){
#pragma unroll
  for(int mt=0;mt<4;++mt){
    f32x16 a = acc[mt];
#pragma unroll
    for(int q=0;q<4;++q){
      f32x4 b = *(const f32x4*)(bo + mt*32 + q*8 + hl*4);
#pragma unroll
      for(int j=0;j<4;++j) a[q*4+j]+=b[j];
    }
#pragma unroll
    for(int r=0;r<16;++r){
      int s=mt*2+(r>>3), i=((r>>2)&1)*4+(r&3);
      a[r] += bf2f(rhi[s][i]) + bf2f(rlo[s][i]);
    }
#pragma unroll
    for(int q=0;q<4;++q){
      f32x4 w; w[0]=a[q*4+0]; w[1]=a[q*4+1]; w[2]=a[q*4+2]; w[3]=a[q*4+3];
      *(f32x4*)(st + (wid*32+c31)*132 + mt*32 + q*8 + hl*4) = w;
    }
  }
  __syncthreads();
#pragma unroll
  for(int i2=0;i2<16;++i2){
    int idx = tid + i2*256; int lr = idx>>5, c4 = idx&31;
    f32x4 v = *(const f32x4*)(st + lr*132 + c4*4);
    size_t off;
    if(predmap){ int row=grow0+lr; int sh=row>>11, b=row&2047; off=((size_t)b*NSHIFT+sh)*NF + c4*4; }
    else       { off=(size_t)(grow0+lr)*NF + c4*4; }
    *(f32x4*)(gout + off) = v;
  }
  __syncthreads();
}

// ---------- main fused kernel: enc resblock + 2x dec resblock + M, 128 rows/block ----------
__global__ __launch_bounds__(256,2)
void k_main2(const float* __restrict__ gin, const unsigned short* __restrict__ swz,
             const float* __restrict__ encB, const float* __restrict__ encBo,
             const float* __restrict__ decB, const float* __restrict__ decBo,
             float* __restrict__ out1, float* __restrict__ out2, float* __restrict__ pe0){
  __shared__ float st[128*132];
  const int tid=threadIdx.x, lane=tid&63, wid=tid>>6;
  const int hl=lane>>5, c31=lane&31;
  const int grow0=blockIdx.x*128;
  const int myrow=grow0 + wid*32 + c31;
  bh8 phi[8],plo[8],hhi[8],hlo[8];
  f32x16 acc[4];
  // x^T frags (per lane: row myrow, two 16B runs per 16-k window)
#pragma unroll
  for(int s=0;s<8;++s){
    f32x4 a=*(const f32x4*)(gin + (size_t)myrow*NF + s*16 + 4*hl);
    f32x4 b=*(const f32x4*)(gin + (size_t)myrow*NF + s*16 + 8 + 4*hl);
    float v[8]={a[0],a[1],a[2],a[3],b[0],b[1],b[2],b[3]};
    split8(v, phi[s], plo[s]);
  }
  // encoder resblock
  run_layer(swz, phi, plo, acc, lane);
  epi<true,true,false>(acc, encB, nullptr, nullptr, hhi, hlo, hl);
#pragma unroll 1
  for(int l=1;l<4;++l){
    run_layer(swz + (size_t)l*32768, hhi, hlo, acc, lane);
    epi<true,true,false>(acc, encB + l*NF, nullptr, nullptr, hhi, hlo, hl);
  }
  run_layer(swz + (size_t)4*32768, hhi, hlo, acc, lane);
  // pe = x + h@Wo + bo  (+ dump t==0 rows for rollout); phi <- pe frags
  {
    int bidx = myrow / LEN_T;
    bool isz = (myrow == bidx*LEN_T);
#pragma unroll
    for(int mt=0;mt<4;++mt){
      f32x16 a = acc[mt];
#pragma unroll
      for(int q=0;q<4;++q){
        f32x4 b = *(const f32x4*)(encBo + mt*32 + q*8 + hl*4);
#pragma unroll
        for(int j=0;j<4;++j) a[q*4+j]+=b[j];
      }
#pragma unroll
      for(int r=0;r<16;++r){
        int s=mt*2+(r>>3), i=((r>>2)&1)*4+(r&3);
        a[r] += bf2f(phi[s][i]) + bf2f(plo[s][i]);
      }
      if(isz){
#pragma unroll
        for(int q=0;q<4;++q){
          f32x4 w; w[0]=a[q*4+0]; w[1]=a[q*4+1]; w[2]=a[q*4+2]; w[3]=a[q*4+3];
          *(f32x4*)(pe0 + (size_t)bidx*NF + mt*32 + q*8 + hl*4) = w;
        }
      }
#pragma unroll
      for(int p=0;p<2;++p){
        float v[8];
#pragma unroll
        for(int i=0;i<8;++i) v[i]=a[p*8 + (i>>2)*4 + (i&3)];
        split8(v, phi[mt*2+p], plo[mt*2+p]);
      }
    }
  }
  // pass A: outer_auto_output = pe + dec(pe)
  dec_layers(swz, decB, phi, plo, hhi, hlo, acc, lane, hl);
  final_stage(st, out2, acc, decBo, phi, plo, tid, wid, c31, hl, grow0, false);
  // pd = pe @ M
  run_layer(swz + (size_t)10*32768, phi, plo, acc, lane);
  epi<false,false,false>(acc, nullptr, nullptr, nullptr, phi, plo, hl);
  // pass B: autoencoder_output = pd + dec(pd)
  dec_layers(swz, decB, phi, plo, hhi, hlo, acc, lane, hl);
  final_stage(st, out1, acc, decBo, phi, plo, tid, wid, c31, hl, grow0, false);
}

// ---------- rollout (f32 exact): z0 = pe0 @ ienc inline, then 50 shifts ----------
__global__ void k_roll(const float* __restrict__ pe0, const float* __restrict__ ienc,
                       const float* __restrict__ L, float* __restrict__ zs){
  const int tid=threadIdx.x, lane=tid&63, wid=tid>>6, sub=lane&31, half=lane>>5;
  const int row=blockIdx.x*8 + wid*2 + half;
  const bool act = sub < NLAT;
  float Lc[NLAT];
#pragma unroll
  for(int k=0;k<NLAT;++k) Lc[k] = act ? L[k*NLAT+sub] : 0.f;
  float z=0.f;
  if(act){
    const float* pr = pe0 + (size_t)row*NF;
    float s0=0.f,s1=0.f,s2=0.f,s3=0.f;
#pragma unroll 8
    for(int k=0;k<NF;k+=4){
      s0=fmaf(pr[k+0], ienc[(k+0)*NLAT+sub], s0);
      s1=fmaf(pr[k+1], ienc[(k+1)*NLAT+sub], s1);
      s2=fmaf(pr[k+2], ienc[(k+2)*NLAT+sub], s2);
      s3=fmaf(pr[k+3], ienc[(k+3)*NLAT+sub], s3);
    }
    z=(s0+s1)+(s2+s3);
  }
  const int base = half*32;
#pragma unroll 1
  for(int s=0;s<NSHIFT;++s){
    float zn=0.f;
#pragma unroll
    for(int k=0;k<NLAT;++k) zn=fmaf(__shfl(z, base+k, 64), Lc[k], zn);
    z=zn;
    if(act) zs[((size_t)s*NBATCH + row)*NLAT + sub] = z;
  }
}

// ---------- prediction decode: dec_in = zs@idec (K=21), then dec resblock ----------
__global__ __launch_bounds__(256,2)
void k_pred2(const float* __restrict__ zs, const unsigned short* __restrict__ swz,
             const float* __restrict__ decB, const float* __restrict__ decBo,
             float* __restrict__ out3){
  __shared__ float st[128*132];
  const int tid=threadIdx.x, lane=tid&63, wid=tid>>6;
  const int hl=lane>>5, c31=lane&31;
  const int grow0=blockIdx.x*128;
  const int prow=grow0 + wid*32 + c31;
  bh8 phi[8],plo[8],hhi[8],hlo[8];
  f32x16 acc[4];
  // z frags (2 windows, guarded loads for K=21)
  bh8 zhi[2], zlo[2];
  {
    const float* zr = zs + (size_t)prow*NLAT;
#pragma unroll
    for(int s=0;s<2;++s){
      float v[8];
#pragma unroll
      for(int i=0;i<8;++i){
        int cc = s*16 + 4*hl + (i&3) + 8*(i>>2);
        v[i] = (cc<NLAT) ? zr[cc] : 0.f;
      }
      split8(v, zhi[s], zlo[s]);
    }
  }
  // dec_in = z @ idec   (A = idec^T swizzled, mat 11; windows 0,1 only)
  {
    const bh8* W = (const bh8*)(swz + (size_t)11*32768);
    f32x16 z;
#pragma unroll
    for(int r=0;r<16;++r) z[r]=0.f;
#pragma unroll
    for(int mt=0;mt<4;++mt) acc[mt]=z;
#pragma unroll
    for(int s=0;s<2;++s)
#pragma unroll
      for(int mt=0;mt<4;++mt){
        bh8 whi=W[(s*4+mt)*64+lane], wlo=W[2048+(s*4+mt)*64+lane];
        acc[mt]=MFMA32(whi,zhi[s],acc[mt]);
        acc[mt]=MFMA32(whi,zlo[s],acc[mt]);
        acc[mt]=MFMA32(wlo,zhi[s],acc[mt]);
      }
  }
  epi<false,false,false>(acc, nullptr, nullptr, nullptr, phi, plo, hl);  // phi = dec_in
  dec_layers(swz, decB, phi, plo, hhi, hlo, acc, lane, hl);
  final_stage(st, out3, acc, decBo, phi, plo, tid, wid, c31, hl, grow0, true);
}

extern "C" void kernel_launch(void* const* d_in, const int* in_sizes, int n_in,
                              void* d_out, int out_size, void* d_ws, size_t ws_size,
                              hipStream_t stream) {
  const float* gin   = (const float*)d_in[0];
  const float* L     = (const float*)d_in[1];
  const float* iencW = (const float*)d_in[2];
  const float* idecW = (const float*)d_in[3];
  const float* encW  = (const float*)d_in[4];
  const float* encB  = (const float*)d_in[5];
  const float* encWo = (const float*)d_in[6];
  const float* encBo = (const float*)d_in[7];
  const float* decW  = (const float*)d_in[8];
  const float* decB  = (const float*)d_in[9];
  const float* decWo = (const float*)d_in[10];
  const float* decBo = (const float*)d_in[11];

  float* out1 = (float*)d_out;                      // autoencoder_output
  float* out2 = out1 + (size_t)AUTO_ROWS*NF;        // outer_auto_output
  float* out3 = out2 + (size_t)AUTO_ROWS*NF;        // predictions

  float* M   = (float*)d_ws;                        // 128*128 f32
  float* pe0 = M + 16384;                           // 2048*128 f32
  float* zs  = pe0 + (size_t)NBATCH*NF;             // 50*2048*21 f32
  unsigned short* swz = (unsigned short*)(zs + (size_t)NSHIFT*NBATCH*NLAT);  // 12*32768 ushort

  hipLaunchKernelGGL(k_mmul, dim3(64),  dim3(256), 0, stream, iencW, idecW, M);
  hipLaunchKernelGGL(k_prep, dim3(96),  dim3(256), 0, stream, encW, encWo, decW, decWo, M, idecW, swz);
  hipLaunchKernelGGL(k_main2, dim3(AUTO_ROWS/128), dim3(256), 0, stream,
                     gin, swz, encB, encBo, decB, decBo, out1, out2, pe0);
  hipLaunchKernelGGL(k_roll, dim3(NBATCH/8), dim3(256), 0, stream, pe0, iencW, L, zs);
  hipLaunchKernelGGL(k_pred2, dim3(PRED_ROWS/128), dim3(256), 0, stream,
                     zs, swz, decB, decBo, out3);
}

// Round 3
// 532.356 us; speedup vs baseline: 1.9575x; 1.4338x over previous
//
#include <hip/hip_runtime.h>

#define NF 128
#define NLAT 21
#define NBATCH 2048
#define LEN_T 51
#define NSHIFT 50
#define AUTO_ROWS (NBATCH*LEN_T)   // 104448
#define PRED_ROWS (NBATCH*NSHIFT)  // 102400

typedef short bh8  __attribute__((ext_vector_type(8)));   // 8 bf16 (A/B frag, 4 VGPR)
typedef unsigned short us8 __attribute__((ext_vector_type(8)));
typedef float f32x4  __attribute__((ext_vector_type(4)));
typedef float f32x16 __attribute__((ext_vector_type(16))); // 32x32 accumulator

#define MFMA32(A,B,C) __builtin_amdgcn_mfma_f32_32x32x16_bf16(A,B,C,0,0,0)

// ---------- helpers ----------
__device__ __forceinline__ float bf2f(short s){
  unsigned u = ((unsigned)(unsigned short)s) << 16;
  return __builtin_bit_cast(float, u);
}
__device__ __forceinline__ void split1(float v, unsigned short& hi, unsigned short& lo){
  unsigned u  = __builtin_bit_cast(unsigned, v);
  unsigned h  = (u + 0x7FFFu + ((u>>16)&1u)) >> 16;          // RNE bf16
  float    l  = v - __builtin_bit_cast(float, h<<16);        // exact residual
  unsigned ul = __builtin_bit_cast(unsigned, l);
  unsigned lw = (ul + 0x7FFFu + ((ul>>16)&1u)) >> 16;        // RNE bf16 of residual
  hi = (unsigned short)h; lo = (unsigned short)lw;
}
__device__ __forceinline__ void split8(const float v[8], bh8& hi, bh8& lo){
#pragma unroll
  for(int i=0;i<8;++i){ unsigned short a,b; split1(v[i],a,b); hi[i]=(short)a; lo[i]=(short)b; }
}

// ---------- prep kernels ----------
__global__ void k_mmul(const float* __restrict__ ienc, const float* __restrict__ idec,
                       float* __restrict__ M){
  int idx = blockIdx.x*256 + threadIdx.x;      // 16384
  int i = idx>>7, j = idx&127;
  float s = 0.f;
#pragma unroll
  for(int k=0;k<NLAT;++k) s = fmaf(ienc[i*NLAT+k], idec[k*NF+j], s);
  M[idx] = s;
}

// swizzled split-bf16 A-operand planes; mats: 0-3 enc_W, 4 enc_Wo, 5-8 dec_W,
// 9 dec_Wo, 10 M, 11 idec^T (K=21 pad).  kappa(h,i)=4h+(i&3)+8(i>>2)
__global__ void k_prep(const float* __restrict__ encW, const float* __restrict__ encWo,
                       const float* __restrict__ decW, const float* __restrict__ decWo,
                       const float* __restrict__ M,    const float* __restrict__ idec,
                       unsigned short* __restrict__ swz){
  int id  = blockIdx.x*256 + threadIdx.x;  // 12 * 2048
  int mat = id >> 11;
  int rem = id & 2047;
  int f   = rem >> 6, l = rem & 63;
  int s   = f >> 2,  mt = f & 3;
  int hl  = l >> 5,  c  = l & 31;
  const float* src;
  if(mat<4)       src = encW + mat*16384;
  else if(mat==4) src = encWo;
  else if(mat<9)  src = decW + (mat-5)*16384;
  else if(mat==9) src = decWo;
  else if(mat==10)src = M;
  else            src = idec;
  us8 hi8, lo8;
#pragma unroll
  for(int i=0;i<8;++i){
    int k = s*16 + 4*hl + (i&3) + 8*(i>>2);
    float v;
    if(mat==11) v = (k<NLAT) ? src[k*NF + mt*32 + c] : 0.f;
    else        v = src[k*NF + mt*32 + c];
    unsigned short a,b; split1(v,a,b); hi8[i]=a; lo8[i]=b;
  }
  size_t base = (size_t)mat*32768 + (size_t)f*512 + (size_t)l*8;
  *(us8*)(swz + base)         = hi8;
  *(us8*)(swz + base + 16384) = lo8;
}

// ---------- core: one 128->128 layer, operands in registers ----------
__device__ __forceinline__ void run_layer(const unsigned short* __restrict__ sw,
    const bh8 hi[8], const bh8 lo[8], f32x16 acc[4], int lane){
  const bh8* W = (const bh8*)sw;
  f32x16 z;
#pragma unroll
  for(int r=0;r<16;++r) z[r]=0.f;
#pragma unroll
  for(int mt=0;mt<4;++mt) acc[mt]=z;
#pragma unroll
  for(int s=0;s<8;++s){
    bh8 bh=hi[s], bl=lo[s];
#pragma unroll
    for(int mt=0;mt<4;++mt){
      bh8 whi = W[(s*4+mt)*64 + lane];
      bh8 wlo = W[2048 + (s*4+mt)*64 + lane];
      acc[mt]=MFMA32(whi,bh,acc[mt]);
      acc[mt]=MFMA32(whi,bl,acc[mt]);
      acc[mt]=MFMA32(wlo,bh,acc[mt]);
    }
  }
}

// hidden-layer epilogue: bias+relu -> split frags in place
__device__ __forceinline__ void epi_hidden(f32x16 acc[4], const float* __restrict__ bias,
    bh8 hhi[8], bh8 hlo[8], int hl){
#pragma unroll
  for(int mt=0;mt<4;++mt){
    f32x16 a = acc[mt];
#pragma unroll
    for(int q=0;q<4;++q){
      f32x4 b = *(const f32x4*)(bias + mt*32 + q*8 + hl*4);
#pragma unroll
      for(int j=0;j<4;++j) a[q*4+j]+=b[j];
    }
#pragma unroll
    for(int r=0;r<16;++r) a[r]=fmaxf(a[r],0.f);
#pragma unroll
    for(int p=0;p<2;++p){
      float v[8];
#pragma unroll
      for(int i=0;i<8;++i) v[i]=a[p*8 + (i>>2)*4 + (i&3)];
      split8(v, hhi[mt*2+p], hlo[mt*2+p]);
    }
  }
}

// plain epilogue: split acc to frags (no bias/relu/residual)
__device__ __forceinline__ void epi_plain(f32x16 acc[4], bh8 hhi[8], bh8 hlo[8], int hl){
#pragma unroll
  for(int mt=0;mt<4;++mt){
    f32x16 a = acc[mt];
#pragma unroll
    for(int p=0;p<2;++p){
      float v[8];
#pragma unroll
      for(int i=0;i<8;++i) v[i]=a[p*8 + (i>>2)*4 + (i&3)];
      split8(v, hhi[mt*2+p], hlo[mt*2+p]);
    }
  }
}

// per-wave LDS frag slice helpers (fb = fragbuf + wid*8192, ushort units)
__device__ __forceinline__ void frag_store(unsigned short* fb, int s,
    const bh8& hi, const bh8& lo, int lane){
  *(bh8*)(fb + s*1024 + lane*8)       = hi;
  *(bh8*)(fb + s*1024 + 512 + lane*8) = lo;
}

// final epilogue: bias + residual(from LDS frags) + direct f32x4 stores
__device__ __forceinline__ void final_direct(float* __restrict__ rowptr,
    f32x16 acc[4], const float* __restrict__ bo,
    const unsigned short* fb, int lane, int hl){
#pragma unroll
  for(int mt=0;mt<4;++mt){
    f32x16 a = acc[mt];
#pragma unroll
    for(int q=0;q<4;++q){
      f32x4 b = *(const f32x4*)(bo + mt*32 + q*8 + hl*4);
#pragma unroll
      for(int j=0;j<4;++j) a[q*4+j]+=b[j];
    }
    bh8 r0h = *(const bh8*)(fb + (2*mt)*1024 + lane*8);
    bh8 r0l = *(const bh8*)(fb + (2*mt)*1024 + 512 + lane*8);
    bh8 r1h = *(const bh8*)(fb + (2*mt+1)*1024 + lane*8);
    bh8 r1l = *(const bh8*)(fb + (2*mt+1)*1024 + 512 + lane*8);
#pragma unroll
    for(int r=0;r<16;++r){
      int i=((r>>2)&1)*4+(r&3);
      float rv = (r<8) ? (bf2f(r0h[i])+bf2f(r0l[i])) : (bf2f(r1h[i])+bf2f(r1l[i]));
      a[r]+=rv;
    }
#pragma unroll
    for(int q=0;q<4;++q){
      f32x4 w; w[0]=a[q*4+0]; w[1]=a[q*4+1]; w[2]=a[q*4+2]; w[3]=a[q*4+3];
      *(f32x4*)(rowptr + mt*32 + q*8 + hl*4) = w;
    }
  }
}

// dec resblock body, in place on hhi/hlo (residual handled by caller)
__device__ __forceinline__ void dec_block(const unsigned short* __restrict__ swz,
    const float* __restrict__ decB, bh8 hhi[8], bh8 hlo[8],
    f32x16 acc[4], int lane, int hl){
  run_layer(swz + (size_t)5*32768, hhi, hlo, acc, lane);
  epi_hidden(acc, decB, hhi, hlo, hl);
#pragma unroll 1
  for(int l=1;l<4;++l){
    run_layer(swz + (size_t)(5+l)*32768, hhi, hlo, acc, lane);
    epi_hidden(acc, decB + l*NF, hhi, hlo, hl);
  }
  run_layer(swz + (size_t)9*32768, hhi, hlo, acc, lane);
}

// ---------- main fused kernel: enc + decA + M + decB, 128 rows/block, no barriers ----------
__global__ __launch_bounds__(256,2)
void k_main2(const float* __restrict__ gin, const unsigned short* __restrict__ swz,
             const float* __restrict__ encB, const float* __restrict__ encBo,
             const float* __restrict__ decB, const float* __restrict__ decBo,
             float* __restrict__ out1, float* __restrict__ out2, float* __restrict__ pe0){
  __shared__ unsigned short fragbuf[32768];  // 64 KB: 4 waves x 8 s x 2 planes x 512
  const int tid=threadIdx.x, lane=tid&63, wid=tid>>6;
  const int hl=lane>>5, c31=lane&31;
  const int grow0=blockIdx.x*128;
  const int myrow=grow0 + wid*32 + c31;
  unsigned short* fb = fragbuf + wid*8192;
  bh8 hhi[8], hlo[8];
  f32x16 acc[4];

  // x frags -> regs + LDS (residual for pe)
#pragma unroll
  for(int s=0;s<8;++s){
    f32x4 a=*(const f32x4*)(gin + (size_t)myrow*NF + s*16 + 4*hl);
    f32x4 b=*(const f32x4*)(gin + (size_t)myrow*NF + s*16 + 8 + 4*hl);
    float v[8]={a[0],a[1],a[2],a[3],b[0],b[1],b[2],b[3]};
    split8(v, hhi[s], hlo[s]);
    frag_store(fb, s, hhi[s], hlo[s], lane);
  }

  // encoder resblock (in place)
  run_layer(swz, hhi, hlo, acc, lane);
  epi_hidden(acc, encB, hhi, hlo, hl);
#pragma unroll 1
  for(int l=1;l<4;++l){
    run_layer(swz + (size_t)l*32768, hhi, hlo, acc, lane);
    epi_hidden(acc, encB + l*NF, hhi, hlo, hl);
  }
  run_layer(swz + (size_t)4*32768, hhi, hlo, acc, lane);

  // pe = x + h@Wo + bo ; dump t==0 rows; frags -> regs + LDS (overwrite x)
  {
    int bidx = myrow / LEN_T;
    bool isz = (myrow == bidx*LEN_T);
#pragma unroll
    for(int mt=0;mt<4;++mt){
      f32x16 a = acc[mt];
#pragma unroll
      for(int q=0;q<4;++q){
        f32x4 b = *(const f32x4*)(encBo + mt*32 + q*8 + hl*4);
#pragma unroll
        for(int j=0;j<4;++j) a[q*4+j]+=b[j];
      }
      bh8 r0h = *(const bh8*)(fb + (2*mt)*1024 + lane*8);
      bh8 r0l = *(const bh8*)(fb + (2*mt)*1024 + 512 + lane*8);
      bh8 r1h = *(const bh8*)(fb + (2*mt+1)*1024 + lane*8);
      bh8 r1l = *(const bh8*)(fb + (2*mt+1)*1024 + 512 + lane*8);
#pragma unroll
      for(int r=0;r<16;++r){
        int i=((r>>2)&1)*4+(r&3);
        float rv = (r<8) ? (bf2f(r0h[i])+bf2f(r0l[i])) : (bf2f(r1h[i])+bf2f(r1l[i]));
        a[r]+=rv;
      }
      if(isz){
#pragma unroll
        for(int q=0;q<4;++q){
          f32x4 w; w[0]=a[q*4+0]; w[1]=a[q*4+1]; w[2]=a[q*4+2]; w[3]=a[q*4+3];
          *(f32x4*)(pe0 + (size_t)bidx*NF + mt*32 + q*8 + hl*4) = w;
        }
      }
#pragma unroll
      for(int p=0;p<2;++p){
        float v[8];
#pragma unroll
        for(int i=0;i<8;++i) v[i]=a[p*8 + (i>>2)*4 + (i&3)];
        split8(v, hhi[mt*2+p], hlo[mt*2+p]);
      }
    }
#pragma unroll
    for(int s=0;s<8;++s) frag_store(fb, s, hhi[s], hlo[s], lane);
  }

  // pass A: outer_auto_output = pe + dec(pe)
  dec_block(swz, decB, hhi, hlo, acc, lane, hl);
  final_direct(out2 + (size_t)myrow*NF, acc, decBo, fb, lane, hl);

  // pd = pe @ M  (reload pe frags from LDS)
#pragma unroll
  for(int s=0;s<8;++s){
    hhi[s]=*(const bh8*)(fb + s*1024 + lane*8);
    hlo[s]=*(const bh8*)(fb + s*1024 + 512 + lane*8);
  }
  run_layer(swz + (size_t)10*32768, hhi, hlo, acc, lane);
  epi_plain(acc, hhi, hlo, hl);
#pragma unroll
  for(int s=0;s<8;++s) frag_store(fb, s, hhi[s], hlo[s], lane);  // pd overwrites pe

  // pass B: autoencoder_output = pd + dec(pd)
  dec_block(swz, decB, hhi, hlo, acc, lane, hl);
  final_direct(out1 + (size_t)myrow*NF, acc, decBo, fb, lane, hl);
}

// ---------- rollout (f32 exact) ----------
__global__ void k_roll(const float* __restrict__ pe0, const float* __restrict__ ienc,
                       const float* __restrict__ L, float* __restrict__ zs){
  const int tid=threadIdx.x, lane=tid&63, wid=tid>>6, sub=lane&31, half=lane>>5;
  const int row=blockIdx.x*8 + wid*2 + half;
  const bool act = sub < NLAT;
  float Lc[NLAT];
#pragma unroll
  for(int k=0;k<NLAT;++k) Lc[k] = act ? L[k*NLAT+sub] : 0.f;
  float z=0.f;
  if(act){
    const float* pr = pe0 + (size_t)row*NF;
    float s0=0.f,s1=0.f,s2=0.f,s3=0.f;
#pragma unroll 8
    for(int k=0;k<NF;k+=4){
      s0=fmaf(pr[k+0], ienc[(k+0)*NLAT+sub], s0);
      s1=fmaf(pr[k+1], ienc[(k+1)*NLAT+sub], s1);
      s2=fmaf(pr[k+2], ienc[(k+2)*NLAT+sub], s2);
      s3=fmaf(pr[k+3], ienc[(k+3)*NLAT+sub], s3);
    }
    z=(s0+s1)+(s2+s3);
  }
  const int base = half*32;
#pragma unroll 1
  for(int s=0;s<NSHIFT;++s){
    float zn=0.f;
#pragma unroll
    for(int k=0;k<NLAT;++k) zn=fmaf(__shfl(z, base+k, 64), Lc[k], zn);
    z=zn;
    if(act) zs[((size_t)s*NBATCH + row)*NLAT + sub] = z;
  }
}

// ---------- prediction decode ----------
__global__ __launch_bounds__(256,2)
void k_pred2(const float* __restrict__ zs, const unsigned short* __restrict__ swz,
             const float* __restrict__ decB, const float* __restrict__ decBo,
             float* __restrict__ out3){
  __shared__ unsigned short fragbuf[32768];
  const int tid=threadIdx.x, lane=tid&63, wid=tid>>6;
  const int hl=lane>>5, c31=lane&31;
  const int grow0=blockIdx.x*128;
  const int prow=grow0 + wid*32 + c31;
  unsigned short* fb = fragbuf + wid*8192;
  bh8 hhi[8], hlo[8];
  f32x16 acc[4];

  // z frags (2 windows, guarded for K=21)
  bh8 zhi[2], zlo[2];
  {
    const float* zr = zs + (size_t)prow*NLAT;
#pragma unroll
    for(int s=0;s<2;++s){
      float v[8];
#pragma unroll
      for(int i=0;i<8;++i){
        int cc = s*16 + 4*hl + (i&3) + 8*(i>>2);
        v[i] = (cc<NLAT) ? zr[cc] : 0.f;
      }
      split8(v, zhi[s], zlo[s]);
    }
  }
  // dec_in = z @ idec (mat 11, windows 0,1)
  {
    const bh8* W = (const bh8*)(swz + (size_t)11*32768);
    f32x16 z;
#pragma unroll
    for(int r=0;r<16;++r) z[r]=0.f;
#pragma unroll
    for(int mt=0;mt<4;++mt) acc[mt]=z;
#pragma unroll
    for(int s=0;s<2;++s)
#pragma unroll
      for(int mt=0;mt<4;++mt){
        bh8 whi=W[(s*4+mt)*64+lane], wlo=W[2048+(s*4+mt)*64+lane];
        acc[mt]=MFMA32(whi,zhi[s],acc[mt]);
        acc[mt]=MFMA32(whi,zlo[s],acc[mt]);
        acc[mt]=MFMA32(wlo,zhi[s],acc[mt]);
      }
  }
  epi_plain(acc, hhi, hlo, hl);   // hhi/hlo = dec_in frags
#pragma unroll
  for(int s=0;s<8;++s) frag_store(fb, s, hhi[s], hlo[s], lane);

  dec_block(swz, decB, hhi, hlo, acc, lane, hl);

  int sh = prow >> 11, b = prow & 2047;
  final_direct(out3 + ((size_t)b*NSHIFT + sh)*NF, acc, decBo, fb, lane, hl);
}

extern "C" void kernel_launch(void* const* d_in, const int* in_sizes, int n_in,
                              void* d_out, int out_size, void* d_ws, size_t ws_size,
                              hipStream_t stream) {
  const float* gin   = (const float*)d_in[0];
  const float* L     = (const float*)d_in[1];
  const float* iencW = (const float*)d_in[2];
  const float* idecW = (const float*)d_in[3];
  const float* encW  = (const float*)d_in[4];
  const float* encB  = (const float*)d_in[5];
  const float* encWo = (const float*)d_in[6];
  const float* encBo = (const float*)d_in[7];
  const float* decW  = (const float*)d_in[8];
  const float* decB  = (const float*)d_in[9];
  const float* decWo = (const float*)d_in[10];
  const float* decBo = (const float*)d_in[11];

  float* out1 = (float*)d_out;                      // autoencoder_output
  float* out2 = out1 + (size_t)AUTO_ROWS*NF;        // outer_auto_output
  float* out3 = out2 + (size_t)AUTO_ROWS*NF;        // predictions

  float* M   = (float*)d_ws;                        // 128*128 f32
  float* pe0 = M + 16384;                           // 2048*128 f32
  float* zs  = pe0 + (size_t)NBATCH*NF;             // 50*2048*21 f32
  unsigned short* swz = (unsigned short*)(zs + (size_t)NSHIFT*NBATCH*NLAT);  // 12*32768 ushort

  hipLaunchKernelGGL(k_mmul, dim3(64),  dim3(256), 0, stream, iencW, idecW, M);
  hipLaunchKernelGGL(k_prep, dim3(96),  dim3(256), 0, stream, encW, encWo, decW, decWo, M, idecW, swz);
  hipLaunchKernelGGL(k_main2, dim3(AUTO_ROWS/128), dim3(256), 0, stream,
                     gin, swz, encB, encBo, decB, decBo, out1, out2, pe0);
  hipLaunchKernelGGL(k_roll, dim3(NBATCH/8), dim3(256), 0, stream, pe0, iencW, L, zs);
  hipLaunchKernelGGL(k_pred2, dim3(PRED_ROWS/128), dim3(256), 0, stream,
                     zs, swz, decB, decBo, out3);
}

// Round 4
// 530.828 us; speedup vs baseline: 1.9632x; 1.0029x over previous
//
#include <hip/hip_runtime.h>

#define NF 128
#define NLAT 21
#define NBATCH 2048
#define LEN_T 51
#define NSHIFT 50
#define AUTO_ROWS (NBATCH*LEN_T)   // 104448
#define PRED_ROWS (NBATCH*NSHIFT)  // 102400

typedef short bh8  __attribute__((ext_vector_type(8)));   // 8 bf16 (A/B frag, 4 VGPR)
typedef unsigned short us8 __attribute__((ext_vector_type(8)));
typedef float f32x4  __attribute__((ext_vector_type(4)));
typedef float f32x16 __attribute__((ext_vector_type(16))); // 32x32 accumulator

#define MFMA32(A,B,C) __builtin_amdgcn_mfma_f32_32x32x16_bf16(A,B,C,0,0,0)
#define SGB(m,n) __builtin_amdgcn_sched_group_barrier((m),(n),0)
// masks: VMEM_READ=0x20, MFMA=0x8

// ---------- helpers ----------
__device__ __forceinline__ float bf2f(short s){
  unsigned u = ((unsigned)(unsigned short)s) << 16;
  return __builtin_bit_cast(float, u);
}
__device__ __forceinline__ void split1(float v, unsigned short& hi, unsigned short& lo){
  unsigned u  = __builtin_bit_cast(unsigned, v);
  unsigned h  = (u + 0x7FFFu + ((u>>16)&1u)) >> 16;          // RNE bf16
  float    l  = v - __builtin_bit_cast(float, h<<16);        // exact residual
  unsigned ul = __builtin_bit_cast(unsigned, l);
  unsigned lw = (ul + 0x7FFFu + ((ul>>16)&1u)) >> 16;        // RNE bf16 of residual
  hi = (unsigned short)h; lo = (unsigned short)lw;
}
__device__ __forceinline__ void split8(const float v[8], bh8& hi, bh8& lo){
#pragma unroll
  for(int i=0;i<8;++i){ unsigned short a,b; split1(v[i],a,b); hi[i]=(short)a; lo[i]=(short)b; }
}

// ---------- prep kernels ----------
__global__ void k_mmul(const float* __restrict__ ienc, const float* __restrict__ idec,
                       float* __restrict__ M){
  int idx = blockIdx.x*256 + threadIdx.x;      // 16384
  int i = idx>>7, j = idx&127;
  float s = 0.f;
#pragma unroll
  for(int k=0;k<NLAT;++k) s = fmaf(ienc[i*NLAT+k], idec[k*NF+j], s);
  M[idx] = s;
}

// swizzled split-bf16 A-operand planes; mats: 0-3 enc_W, 4 enc_Wo, 5-8 dec_W,
// 9 dec_Wo, 10 M, 11 idec^T (K=21 pad).  kappa(h,i)=4h+(i&3)+8(i>>2)
__global__ void k_prep(const float* __restrict__ encW, const float* __restrict__ encWo,
                       const float* __restrict__ decW, const float* __restrict__ decWo,
                       const float* __restrict__ M,    const float* __restrict__ idec,
                       unsigned short* __restrict__ swz){
  int id  = blockIdx.x*256 + threadIdx.x;  // 12 * 2048
  int mat = id >> 11;
  int rem = id & 2047;
  int f   = rem >> 6, l = rem & 63;
  int s   = f >> 2,  mt = f & 3;
  int hl  = l >> 5,  c  = l & 31;
  const float* src;
  if(mat<4)       src = encW + mat*16384;
  else if(mat==4) src = encWo;
  else if(mat<9)  src = decW + (mat-5)*16384;
  else if(mat==9) src = decWo;
  else if(mat==10)src = M;
  else            src = idec;
  us8 hi8, lo8;
#pragma unroll
  for(int i=0;i<8;++i){
    int k = s*16 + 4*hl + (i&3) + 8*(i>>2);
    float v;
    if(mat==11) v = (k<NLAT) ? src[k*NF + mt*32 + c] : 0.f;
    else        v = src[k*NF + mt*32 + c];
    unsigned short a,b; split1(v,a,b); hi8[i]=a; lo8[i]=b;
  }
  size_t base = (size_t)mat*32768 + (size_t)f*512 + (size_t)l*8;
  *(us8*)(swz + base)         = hi8;
  *(us8*)(swz + base + 16384) = lo8;
}

// ---------- W fragment load + MFMA group primitives ----------
__device__ __forceinline__ void ldw(const bh8* __restrict__ Wh, const bh8* __restrict__ Wl,
                                    int s, int lane, bh8 wh[4], bh8 wl[4]){
#pragma unroll
  for(int mt=0;mt<4;++mt){ wh[mt]=Wh[(s*4+mt)*64+lane]; wl[mt]=Wl[(s*4+mt)*64+lane]; }
}
__device__ __forceinline__ void mm(const bh8 wh[4], const bh8 wl[4],
                                   bh8 bh, bh8 bl, f32x16 acc[4]){
#pragma unroll
  for(int mt=0;mt<4;++mt){
    acc[mt]=MFMA32(wh[mt],bh,acc[mt]);
    acc[mt]=MFMA32(wh[mt],bl,acc[mt]);
    acc[mt]=MFMA32(wl[mt],bh,acc[mt]);
  }
}

// ---------- core: one 128->128 layer, SGB-pinned depth-1 pipeline ----------
__device__ __forceinline__ void run_layer(const unsigned short* __restrict__ sw,
    const bh8 hi[8], const bh8 lo[8], f32x16 acc[4], int lane){
  const bh8* Wh = (const bh8*)sw;
  const bh8* Wl = Wh + 2048;
#pragma unroll
  for(int mt=0;mt<4;++mt){
    f32x16 z;
#pragma unroll
    for(int r=0;r<16;++r) z[r]=0.f;
    acc[mt]=z;
  }
  bh8 wAh[4],wAl[4],wBh[4],wBl[4];
  ldw(Wh,Wl,0,lane,wAh,wAl);    SGB(0x20,8);
  ldw(Wh,Wl,1,lane,wBh,wBl);    SGB(0x20,8);
  mm(wAh,wAl,hi[0],lo[0],acc);  SGB(0x8,12);
  ldw(Wh,Wl,2,lane,wAh,wAl);    SGB(0x20,8);
  mm(wBh,wBl,hi[1],lo[1],acc);  SGB(0x8,12);
  ldw(Wh,Wl,3,lane,wBh,wBl);    SGB(0x20,8);
  mm(wAh,wAl,hi[2],lo[2],acc);  SGB(0x8,12);
  ldw(Wh,Wl,4,lane,wAh,wAl);    SGB(0x20,8);
  mm(wBh,wBl,hi[3],lo[3],acc);  SGB(0x8,12);
  ldw(Wh,Wl,5,lane,wBh,wBl);    SGB(0x20,8);
  mm(wAh,wAl,hi[4],lo[4],acc);  SGB(0x8,12);
  ldw(Wh,Wl,6,lane,wAh,wAl);    SGB(0x20,8);
  mm(wBh,wBl,hi[5],lo[5],acc);  SGB(0x8,12);
  ldw(Wh,Wl,7,lane,wBh,wBl);    SGB(0x20,8);
  mm(wAh,wAl,hi[6],lo[6],acc);  SGB(0x8,12);
  mm(wBh,wBl,hi[7],lo[7],acc);  SGB(0x8,12);
}

// hidden-layer epilogue: bias+relu -> split frags in place
__device__ __forceinline__ void epi_hidden(f32x16 acc[4], const float* __restrict__ bias,
    bh8 hhi[8], bh8 hlo[8], int hl){
#pragma unroll
  for(int mt=0;mt<4;++mt){
    f32x16 a = acc[mt];
#pragma unroll
    for(int q=0;q<4;++q){
      f32x4 b = *(const f32x4*)(bias + mt*32 + q*8 + hl*4);
#pragma unroll
      for(int j=0;j<4;++j) a[q*4+j]+=b[j];
    }
#pragma unroll
    for(int r=0;r<16;++r) a[r]=fmaxf(a[r],0.f);
#pragma unroll
    for(int p=0;p<2;++p){
      float v[8];
#pragma unroll
      for(int i=0;i<8;++i) v[i]=a[p*8 + (i>>2)*4 + (i&3)];
      split8(v, hhi[mt*2+p], hlo[mt*2+p]);
    }
  }
}

// plain epilogue: split acc to frags (no bias/relu/residual)
__device__ __forceinline__ void epi_plain(f32x16 acc[4], bh8 hhi[8], bh8 hlo[8], int hl){
#pragma unroll
  for(int mt=0;mt<4;++mt){
    f32x16 a = acc[mt];
#pragma unroll
    for(int p=0;p<2;++p){
      float v[8];
#pragma unroll
      for(int i=0;i<8;++i) v[i]=a[p*8 + (i>>2)*4 + (i&3)];
      split8(v, hhi[mt*2+p], hlo[mt*2+p]);
    }
  }
}

// per-wave LDS frag slice helpers (fb = fragbuf + wid*8192, ushort units)
__device__ __forceinline__ void frag_store(unsigned short* fb, int s,
    const bh8& hi, const bh8& lo, int lane){
  *(bh8*)(fb + s*1024 + lane*8)       = hi;
  *(bh8*)(fb + s*1024 + 512 + lane*8) = lo;
}

// final epilogue: bias + residual(from LDS frags) + direct f32x4 stores
__device__ __forceinline__ void final_direct(float* __restrict__ rowptr,
    f32x16 acc[4], const float* __restrict__ bo,
    const unsigned short* fb, int lane, int hl){
#pragma unroll
  for(int mt=0;mt<4;++mt){
    f32x16 a = acc[mt];
#pragma unroll
    for(int q=0;q<4;++q){
      f32x4 b = *(const f32x4*)(bo + mt*32 + q*8 + hl*4);
#pragma unroll
      for(int j=0;j<4;++j) a[q*4+j]+=b[j];
    }
    bh8 r0h = *(const bh8*)(fb + (2*mt)*1024 + lane*8);
    bh8 r0l = *(const bh8*)(fb + (2*mt)*1024 + 512 + lane*8);
    bh8 r1h = *(const bh8*)(fb + (2*mt+1)*1024 + lane*8);
    bh8 r1l = *(const bh8*)(fb + (2*mt+1)*1024 + 512 + lane*8);
#pragma unroll
    for(int r=0;r<16;++r){
      int i=((r>>2)&1)*4+(r&3);
      float rv = (r<8) ? (bf2f(r0h[i])+bf2f(r0l[i])) : (bf2f(r1h[i])+bf2f(r1l[i]));
      a[r]+=rv;
    }
#pragma unroll
    for(int q=0;q<4;++q){
      f32x4 w; w[0]=a[q*4+0]; w[1]=a[q*4+1]; w[2]=a[q*4+2]; w[3]=a[q*4+3];
      *(f32x4*)(rowptr + mt*32 + q*8 + hl*4) = w;
    }
  }
}

// dec resblock body, in place on hhi/hlo (residual handled by caller)
__device__ __forceinline__ void dec_block(const unsigned short* __restrict__ swz,
    const float* __restrict__ decB, bh8 hhi[8], bh8 hlo[8],
    f32x16 acc[4], int lane, int hl){
  run_layer(swz + (size_t)5*32768, hhi, hlo, acc, lane);
  epi_hidden(acc, decB, hhi, hlo, hl);
#pragma unroll 1
  for(int l=1;l<4;++l){
    run_layer(swz + (size_t)(5+l)*32768, hhi, hlo, acc, lane);
    epi_hidden(acc, decB + l*NF, hhi, hlo, hl);
  }
  run_layer(swz + (size_t)9*32768, hhi, hlo, acc, lane);
}

// ---------- main fused kernel: enc + decA + M + decB, 128 rows/block, no barriers ----------
__global__ __launch_bounds__(256,2)
void k_main2(const float* __restrict__ gin, const unsigned short* __restrict__ swz,
             const float* __restrict__ encB, const float* __restrict__ encBo,
             const float* __restrict__ decB, const float* __restrict__ decBo,
             float* __restrict__ out1, float* __restrict__ out2, float* __restrict__ pe0){
  __shared__ unsigned short fragbuf[32768];  // 64 KB: 4 waves x 8 s x 2 planes x 512
  const int tid=threadIdx.x, lane=tid&63, wid=tid>>6;
  const int hl=lane>>5, c31=lane&31;
  const int grow0=blockIdx.x*128;
  const int myrow=grow0 + wid*32 + c31;
  unsigned short* fb = fragbuf + wid*8192;
  bh8 hhi[8], hlo[8];
  f32x16 acc[4];

  // x frags -> regs + LDS (residual for pe)
#pragma unroll
  for(int s=0;s<8;++s){
    f32x4 a=*(const f32x4*)(gin + (size_t)myrow*NF + s*16 + 4*hl);
    f32x4 b=*(const f32x4*)(gin + (size_t)myrow*NF + s*16 + 8 + 4*hl);
    float v[8]={a[0],a[1],a[2],a[3],b[0],b[1],b[2],b[3]};
    split8(v, hhi[s], hlo[s]);
    frag_store(fb, s, hhi[s], hlo[s], lane);
  }

  // encoder resblock (in place)
  run_layer(swz, hhi, hlo, acc, lane);
  epi_hidden(acc, encB, hhi, hlo, hl);
#pragma unroll 1
  for(int l=1;l<4;++l){
    run_layer(swz + (size_t)l*32768, hhi, hlo, acc, lane);
    epi_hidden(acc, encB + l*NF, hhi, hlo, hl);
  }
  run_layer(swz + (size_t)4*32768, hhi, hlo, acc, lane);

  // pe = x + h@Wo + bo ; dump t==0 rows; frags -> regs + LDS (overwrite x)
  {
    int bidx = myrow / LEN_T;
    bool isz = (myrow == bidx*LEN_T);
#pragma unroll
    for(int mt=0;mt<4;++mt){
      f32x16 a = acc[mt];
#pragma unroll
      for(int q=0;q<4;++q){
        f32x4 b = *(const f32x4*)(encBo + mt*32 + q*8 + hl*4);
#pragma unroll
        for(int j=0;j<4;++j) a[q*4+j]+=b[j];
      }
      bh8 r0h = *(const bh8*)(fb + (2*mt)*1024 + lane*8);
      bh8 r0l = *(const bh8*)(fb + (2*mt)*1024 + 512 + lane*8);
      bh8 r1h = *(const bh8*)(fb + (2*mt+1)*1024 + lane*8);
      bh8 r1l = *(const bh8*)(fb + (2*mt+1)*1024 + 512 + lane*8);
#pragma unroll
      for(int r=0;r<16;++r){
        int i=((r>>2)&1)*4+(r&3);
        float rv = (r<8) ? (bf2f(r0h[i])+bf2f(r0l[i])) : (bf2f(r1h[i])+bf2f(r1l[i]));
        a[r]+=rv;
      }
      if(isz){
#pragma unroll
        for(int q=0;q<4;++q){
          f32x4 w; w[0]=a[q*4+0]; w[1]=a[q*4+1]; w[2]=a[q*4+2]; w[3]=a[q*4+3];
          *(f32x4*)(pe0 + (size_t)bidx*NF + mt*32 + q*8 + hl*4) = w;
        }
      }
#pragma unroll
      for(int p=0;p<2;++p){
        float v[8];
#pragma unroll
        for(int i=0;i<8;++i) v[i]=a[p*8 + (i>>2)*4 + (i&3)];
        split8(v, hhi[mt*2+p], hlo[mt*2+p]);
      }
    }
#pragma unroll
    for(int s=0;s<8;++s) frag_store(fb, s, hhi[s], hlo[s], lane);
  }

  // pass A: outer_auto_output = pe + dec(pe)
  dec_block(swz, decB, hhi, hlo, acc, lane, hl);
  final_direct(out2 + (size_t)myrow*NF, acc, decBo, fb, lane, hl);

  // pd = pe @ M  (reload pe frags from LDS)
#pragma unroll
  for(int s=0;s<8;++s){
    hhi[s]=*(const bh8*)(fb + s*1024 + lane*8);
    hlo[s]=*(const bh8*)(fb + s*1024 + 512 + lane*8);
  }
  run_layer(swz + (size_t)10*32768, hhi, hlo, acc, lane);
  epi_plain(acc, hhi, hlo, hl);
#pragma unroll
  for(int s=0;s<8;++s) frag_store(fb, s, hhi[s], hlo[s], lane);  // pd overwrites pe

  // pass B: autoencoder_output = pd + dec(pd)
  dec_block(swz, decB, hhi, hlo, acc, lane, hl);
  final_direct(out1 + (size_t)myrow*NF, acc, decBo, fb, lane, hl);
}

// ---------- rollout (f32 exact) ----------
__global__ void k_roll(const float* __restrict__ pe0, const float* __restrict__ ienc,
                       const float* __restrict__ L, float* __restrict__ zs){
  const int tid=threadIdx.x, lane=tid&63, wid=tid>>6, sub=lane&31, half=lane>>5;
  const int row=blockIdx.x*8 + wid*2 + half;
  const bool act = sub < NLAT;
  float Lc[NLAT];
#pragma unroll
  for(int k=0;k<NLAT;++k) Lc[k] = act ? L[k*NLAT+sub] : 0.f;
  float z=0.f;
  if(act){
    const float* pr = pe0 + (size_t)row*NF;
    float s0=0.f,s1=0.f,s2=0.f,s3=0.f;
#pragma unroll 8
    for(int k=0;k<NF;k+=4){
      s0=fmaf(pr[k+0], ienc[(k+0)*NLAT+sub], s0);
      s1=fmaf(pr[k+1], ienc[(k+1)*NLAT+sub], s1);
      s2=fmaf(pr[k+2], ienc[(k+2)*NLAT+sub], s2);
      s3=fmaf(pr[k+3], ienc[(k+3)*NLAT+sub], s3);
    }
    z=(s0+s1)+(s2+s3);
  }
  const int base = half*32;
#pragma unroll 1
  for(int s=0;s<NSHIFT;++s){
    float zn=0.f;
#pragma unroll
    for(int k=0;k<NLAT;++k) zn=fmaf(__shfl(z, base+k, 64), Lc[k], zn);
    z=zn;
    if(act) zs[((size_t)s*NBATCH + row)*NLAT + sub] = z;
  }
}

// ---------- prediction decode ----------
__global__ __launch_bounds__(256,2)
void k_pred2(const float* __restrict__ zs, const unsigned short* __restrict__ swz,
             const float* __restrict__ decB, const float* __restrict__ decBo,
             float* __restrict__ out3){
  __shared__ unsigned short fragbuf[32768];
  const int tid=threadIdx.x, lane=tid&63, wid=tid>>6;
  const int hl=lane>>5, c31=lane&31;
  const int grow0=blockIdx.x*128;
  const int prow=grow0 + wid*32 + c31;
  unsigned short* fb = fragbuf + wid*8192;
  bh8 hhi[8], hlo[8];
  f32x16 acc[4];

  // z frags (2 windows, guarded for K=21)
  bh8 zhi[2], zlo[2];
  {
    const float* zr = zs + (size_t)prow*NLAT;
#pragma unroll
    for(int s=0;s<2;++s){
      float v[8];
#pragma unroll
      for(int i=0;i<8;++i){
        int cc = s*16 + 4*hl + (i&3) + 8*(i>>2);
        v[i] = (cc<NLAT) ? zr[cc] : 0.f;
      }
      split8(v, zhi[s], zlo[s]);
    }
  }
  // dec_in = z @ idec (mat 11, windows 0,1) — SGB-pinned like run_layer
  {
    const bh8* Wh = (const bh8*)(swz + (size_t)11*32768);
    const bh8* Wl = Wh + 2048;
#pragma unroll
    for(int mt=0;mt<4;++mt){
      f32x16 z;
#pragma unroll
      for(int r=0;r<16;++r) z[r]=0.f;
      acc[mt]=z;
    }
    bh8 wAh[4],wAl[4],wBh[4],wBl[4];
    ldw(Wh,Wl,0,lane,wAh,wAl);      SGB(0x20,8);
    ldw(Wh,Wl,1,lane,wBh,wBl);      SGB(0x20,8);
    mm(wAh,wAl,zhi[0],zlo[0],acc);  SGB(0x8,12);
    mm(wBh,wBl,zhi[1],zlo[1],acc);  SGB(0x8,12);
  }
  epi_plain(acc, hhi, hlo, hl);   // hhi/hlo = dec_in frags
#pragma unroll
  for(int s=0;s<8;++s) frag_store(fb, s, hhi[s], hlo[s], lane);

  dec_block(swz, decB, hhi, hlo, acc, lane, hl);

  int sh = prow >> 11, b = prow & 2047;
  final_direct(out3 + ((size_t)b*NSHIFT + sh)*NF, acc, decBo, fb, lane, hl);
}

extern "C" void kernel_launch(void* const* d_in, const int* in_sizes, int n_in,
                              void* d_out, int out_size, void* d_ws, size_t ws_size,
                              hipStream_t stream) {
  const float* gin   = (const float*)d_in[0];
  const float* L     = (const float*)d_in[1];
  const float* iencW = (const float*)d_in[2];
  const float* idecW = (const float*)d_in[3];
  const float* encW  = (const float*)d_in[4];
  const float* encB  = (const float*)d_in[5];
  const float* encWo = (const float*)d_in[6];
  const float* encBo = (const float*)d_in[7];
  const float* decW  = (const float*)d_in[8];
  const float* decB  = (const float*)d_in[9];
  const float* decWo = (const float*)d_in[10];
  const float* decBo = (const float*)d_in[11];

  float* out1 = (float*)d_out;                      // autoencoder_output
  float* out2 = out1 + (size_t)AUTO_ROWS*NF;        // outer_auto_output
  float* out3 = out2 + (size_t)AUTO_ROWS*NF;        // predictions

  float* M   = (float*)d_ws;                        // 128*128 f32
  float* pe0 = M + 16384;                           // 2048*128 f32
  float* zs  = pe0 + (size_t)NBATCH*NF;             // 50*2048*21 f32
  unsigned short* swz = (unsigned short*)(zs + (size_t)NSHIFT*NBATCH*NLAT);  // 12*32768 ushort

  hipLaunchKernelGGL(k_mmul, dim3(64),  dim3(256), 0, stream, iencW, idecW, M);
  hipLaunchKernelGGL(k_prep, dim3(96),  dim3(256), 0, stream, encW, encWo, decW, decWo, M, idecW, swz);
  hipLaunchKernelGGL(k_main2, dim3(AUTO_ROWS/128), dim3(256), 0, stream,
                     gin, swz, encB, encBo, decB, decBo, out1, out2, pe0);
  hipLaunchKernelGGL(k_roll, dim3(NBATCH/8), dim3(256), 0, stream, pe0, iencW, L, zs);
  hipLaunchKernelGGL(k_pred2, dim3(PRED_ROWS/128), dim3(256), 0, stream,
                     zs, swz, decB, decBo, out3);
}

// Round 5
// 179.322 us; speedup vs baseline: 5.8113x; 2.9602x over previous
//
#include <hip/hip_runtime.h>

#define NF 128
#define NLAT 21
#define NBATCH 2048
#define LEN_T 51
#define NSHIFT 50
#define AUTO_ROWS (NBATCH*LEN_T)   // 104448
#define PRED_ROWS (NBATCH*NSHIFT)  // 102400

typedef short bh8  __attribute__((ext_vector_type(8)));   // 8 bf16 (A/B frag, 4 VGPR)
typedef unsigned short us8 __attribute__((ext_vector_type(8)));
typedef float f32x4  __attribute__((ext_vector_type(4)));
typedef float f32x16 __attribute__((ext_vector_type(16))); // 32x32 accumulator

#define MFMA32(A,B,C) __builtin_amdgcn_mfma_f32_32x32x16_bf16(A,B,C,0,0,0)
#define SGB(m,n) __builtin_amdgcn_sched_group_barrier((m),(n),0)
// masks: DS_READ=0x100, MFMA=0x8

// ---------- helpers ----------
__device__ __forceinline__ float bf2f(short s){
  unsigned u = ((unsigned)(unsigned short)s) << 16;
  return __builtin_bit_cast(float, u);
}
__device__ __forceinline__ short f2bf(float v){
  unsigned u = __builtin_bit_cast(unsigned, v);
  return (short)((u + 0x7FFFu + ((u>>16)&1u)) >> 16);   // RNE
}

// ---------- prep kernels ----------
__global__ void k_mmul(const float* __restrict__ ienc, const float* __restrict__ idec,
                       float* __restrict__ M){
  int idx = blockIdx.x*256 + threadIdx.x;      // 16384
  int i = idx>>7, j = idx&127;
  float s = 0.f;
#pragma unroll
  for(int k=0;k<NLAT;++k) s = fmaf(ienc[i*NLAT+k], idec[k*NF+j], s);
  M[idx] = s;
}

// swizzled bf16 A-operand planes (single plane); mats: 0-3 enc_W, 4 enc_Wo,
// 5-8 dec_W, 9 dec_Wo, 10 M, 11 idec^T (K=21 pad). kappa(h,i)=4h+(i&3)+8(i>>2)
// layout (ushort): mat*16384 + (s*4+mt)*512 + lane*8
__global__ void k_prep(const float* __restrict__ encW, const float* __restrict__ encWo,
                       const float* __restrict__ decW, const float* __restrict__ decWo,
                       const float* __restrict__ M,    const float* __restrict__ idec,
                       unsigned short* __restrict__ swz){
  int id  = blockIdx.x*256 + threadIdx.x;  // 12 * 2048
  int mat = id >> 11;
  int rem = id & 2047;
  int f   = rem >> 6, l = rem & 63;
  int s   = f >> 2,  mt = f & 3;
  int hl  = l >> 5,  c  = l & 31;
  const float* src;
  if(mat<4)       src = encW + mat*16384;
  else if(mat==4) src = encWo;
  else if(mat<9)  src = decW + (mat-5)*16384;
  else if(mat==9) src = decWo;
  else if(mat==10)src = M;
  else            src = idec;
  us8 w8;
#pragma unroll
  for(int i=0;i<8;++i){
    int k = s*16 + 4*hl + (i&3) + 8*(i>>2);
    float v;
    if(mat==11) v = (k<NLAT) ? src[k*NF + mt*32 + c] : 0.f;
    else        v = src[k*NF + mt*32 + c];
    w8[i] = (unsigned short)f2bf(v);
  }
  *(us8*)(swz + (size_t)mat*16384 + (size_t)f*512 + (size_t)l*8) = w8;
}

// ---------- W staging: global -> shared (32 KB), block-wide ----------
__device__ __forceinline__ void stage_w(const unsigned short* __restrict__ g,
                                        unsigned short* l, int tid){
  __syncthreads();   // everyone done reading previous matrix
#pragma unroll
  for(int i=0;i<8;++i)
    *(us8*)(l + i*2048 + tid*8) = *(const us8*)(g + i*2048 + tid*8);
  __syncthreads();
}

// ---------- core: one 128->128 layer, W frags from LDS, depth-1 dbuf ----------
__device__ __forceinline__ void ldw4(const unsigned short* wl, int s, int lane, bh8 w[4]){
#pragma unroll
  for(int mt=0;mt<4;++mt) w[mt] = *(const bh8*)(wl + (s*4+mt)*512 + lane*8);
}
__device__ __forceinline__ void mm4(const bh8 w[4], bh8 b, f32x16 acc[4]){
#pragma unroll
  for(int mt=0;mt<4;++mt) acc[mt]=MFMA32(w[mt],b,acc[mt]);
}
__device__ __forceinline__ void run_layer(const unsigned short* wl,
    const bh8 h[8], f32x16 acc[4], int lane){
#pragma unroll
  for(int mt=0;mt<4;++mt){
    f32x16 z;
#pragma unroll
    for(int r=0;r<16;++r) z[r]=0.f;
    acc[mt]=z;
  }
  bh8 wA[4], wB[4];
  ldw4(wl,0,lane,wA);   SGB(0x100,4);
  ldw4(wl,1,lane,wB);   SGB(0x100,4);
  mm4(wA,h[0],acc);     SGB(0x8,4);
  ldw4(wl,2,lane,wA);   SGB(0x100,4);
  mm4(wB,h[1],acc);     SGB(0x8,4);
  ldw4(wl,3,lane,wB);   SGB(0x100,4);
  mm4(wA,h[2],acc);     SGB(0x8,4);
  ldw4(wl,4,lane,wA);   SGB(0x100,4);
  mm4(wB,h[3],acc);     SGB(0x8,4);
  ldw4(wl,5,lane,wB);   SGB(0x100,4);
  mm4(wA,h[4],acc);     SGB(0x8,4);
  ldw4(wl,6,lane,wA);   SGB(0x100,4);
  mm4(wB,h[5],acc);     SGB(0x8,4);
  ldw4(wl,7,lane,wB);   SGB(0x100,4);
  mm4(wA,h[6],acc);     SGB(0x8,4);
  mm4(wB,h[7],acc);     SGB(0x8,4);
}

// hidden-layer epilogue: bias+relu -> bf16 frags
__device__ __forceinline__ void epi_hidden(f32x16 acc[4], const float* __restrict__ bias,
    bh8 h[8], int hl){
#pragma unroll
  for(int mt=0;mt<4;++mt){
    f32x16 a = acc[mt];
#pragma unroll
    for(int q=0;q<4;++q){
      f32x4 b = *(const f32x4*)(bias + mt*32 + q*8 + hl*4);
#pragma unroll
      for(int j=0;j<4;++j) a[q*4+j]+=b[j];
    }
#pragma unroll
    for(int r=0;r<16;++r) a[r]=fmaxf(a[r],0.f);
#pragma unroll
    for(int p=0;p<2;++p){
      bh8 o;
#pragma unroll
      for(int i=0;i<8;++i) o[i]=f2bf(a[p*8 + (i>>2)*4 + (i&3)]);
      h[mt*2+p]=o;
    }
  }
}
// plain epilogue (no bias/relu)
__device__ __forceinline__ void epi_plain(f32x16 acc[4], bh8 h[8], int hl){
#pragma unroll
  for(int mt=0;mt<4;++mt){
    f32x16 a = acc[mt];
#pragma unroll
    for(int p=0;p<2;++p){
      bh8 o;
#pragma unroll
      for(int i=0;i<8;++i) o[i]=f2bf(a[p*8 + (i>>2)*4 + (i&3)]);
      h[mt*2+p]=o;
    }
  }
}

// per-wave residual slice (fb = fragbuf + wid*4096 ushorts)
__device__ __forceinline__ void frag_store(unsigned short* fb, int s, const bh8& v, int lane){
  *(bh8*)(fb + s*512 + lane*8) = v;
}
__device__ __forceinline__ bh8 frag_load(const unsigned short* fb, int s, int lane){
  return *(const bh8*)(fb + s*512 + lane*8);
}

// final epilogue: bias + residual(bf16 from LDS) + direct f32x4 stores
__device__ __forceinline__ void final_direct(float* __restrict__ rowptr,
    f32x16 acc[4], const float* __restrict__ bo,
    const unsigned short* fb, int lane, int hl){
#pragma unroll
  for(int mt=0;mt<4;++mt){
    f32x16 a = acc[mt];
#pragma unroll
    for(int q=0;q<4;++q){
      f32x4 b = *(const f32x4*)(bo + mt*32 + q*8 + hl*4);
#pragma unroll
      for(int j=0;j<4;++j) a[q*4+j]+=b[j];
    }
    bh8 r0 = frag_load(fb, 2*mt,   lane);
    bh8 r1 = frag_load(fb, 2*mt+1, lane);
#pragma unroll
    for(int r=0;r<16;++r){
      int i=((r>>2)&1)*4+(r&3);
      a[r] += bf2f(r<8 ? r0[i] : r1[i]);
    }
#pragma unroll
    for(int q=0;q<4;++q){
      f32x4 w; w[0]=a[q*4+0]; w[1]=a[q*4+1]; w[2]=a[q*4+2]; w[3]=a[q*4+3];
      *(f32x4*)(rowptr + mt*32 + q*8 + hl*4) = w;
    }
  }
}

// dec resblock body: 4 relu layers + linear Wo (staged per layer)
__device__ __forceinline__ void dec_block(const unsigned short* __restrict__ swz,
    unsigned short* wlds, const float* __restrict__ decB,
    bh8 h[8], f32x16 acc[4], int tid, int lane, int hl){
#pragma unroll 1
  for(int l=0;l<4;++l){
    stage_w(swz + (size_t)(5+l)*16384, wlds, tid);
    run_layer(wlds, h, acc, lane);
    epi_hidden(acc, decB + l*NF, h, hl);
  }
  stage_w(swz + (size_t)9*16384, wlds, tid);
  run_layer(wlds, h, acc, lane);
}

// ---------- main fused kernel ----------
__global__ __launch_bounds__(256,2)
void k_main2(const float* __restrict__ gin, const unsigned short* __restrict__ swz,
             const float* __restrict__ encB, const float* __restrict__ encBo,
             const float* __restrict__ decB, const float* __restrict__ decBo,
             float* __restrict__ out1, float* __restrict__ out2, float* __restrict__ pe0){
  __shared__ unsigned short wlds[16384];       // 32 KB staged W
  __shared__ unsigned short fragbuf[16384];    // 32 KB: 4 waves x 8 s x 512
  const int tid=threadIdx.x, lane=tid&63, wid=tid>>6;
  const int hl=lane>>5, c31=lane&31;
  const int grow0=blockIdx.x*128;
  const int myrow=grow0 + wid*32 + c31;
  unsigned short* fb = fragbuf + wid*4096;
  bh8 h[8];
  f32x16 acc[4];

  // x frags -> regs + LDS residual
#pragma unroll
  for(int s=0;s<8;++s){
    f32x4 a=*(const f32x4*)(gin + (size_t)myrow*NF + s*16 + 4*hl);
    f32x4 b=*(const f32x4*)(gin + (size_t)myrow*NF + s*16 + 8 + 4*hl);
    bh8 o;
#pragma unroll
    for(int i=0;i<4;++i){ o[i]=f2bf(a[i]); o[i+4]=f2bf(b[i]); }
    h[s]=o;
    frag_store(fb, s, o, lane);
  }

  // encoder resblock
#pragma unroll 1
  for(int l=0;l<4;++l){
    stage_w(swz + (size_t)l*16384, wlds, tid);
    run_layer(wlds, h, acc, lane);
    epi_hidden(acc, encB + l*NF, h, hl);
  }
  stage_w(swz + (size_t)4*16384, wlds, tid);
  run_layer(wlds, h, acc, lane);

  // pe = x + h@Wo + bo ; dump t==0 rows to pe0; h <- pe; fb <- pe
  {
    int bidx = myrow / LEN_T;
    bool isz = (myrow == bidx*LEN_T);
#pragma unroll
    for(int mt=0;mt<4;++mt){
      f32x16 a = acc[mt];
#pragma unroll
      for(int q=0;q<4;++q){
        f32x4 b = *(const f32x4*)(encBo + mt*32 + q*8 + hl*4);
#pragma unroll
        for(int j=0;j<4;++j) a[q*4+j]+=b[j];
      }
      bh8 r0 = frag_load(fb, 2*mt,   lane);
      bh8 r1 = frag_load(fb, 2*mt+1, lane);
#pragma unroll
      for(int r=0;r<16;++r){
        int i=((r>>2)&1)*4+(r&3);
        a[r] += bf2f(r<8 ? r0[i] : r1[i]);
      }
      if(isz){
#pragma unroll
        for(int q=0;q<4;++q){
          f32x4 w; w[0]=a[q*4+0]; w[1]=a[q*4+1]; w[2]=a[q*4+2]; w[3]=a[q*4+3];
          *(f32x4*)(pe0 + (size_t)bidx*NF + mt*32 + q*8 + hl*4) = w;
        }
      }
#pragma unroll
      for(int p=0;p<2;++p){
        bh8 o;
#pragma unroll
        for(int i=0;i<8;++i) o[i]=f2bf(a[p*8 + (i>>2)*4 + (i&3)]);
        h[mt*2+p]=o;
      }
    }
#pragma unroll
    for(int s=0;s<8;++s) frag_store(fb, s, h[s], lane);
  }

  // pass A: outer_auto_output = pe + dec(pe)
  dec_block(swz, wlds, decB, h, acc, tid, lane, hl);
  final_direct(out2 + (size_t)myrow*NF, acc, decBo, fb, lane, hl);

  // pd = pe @ M (reload pe frags from LDS)
#pragma unroll
  for(int s=0;s<8;++s) h[s]=frag_load(fb, s, lane);
  stage_w(swz + (size_t)10*16384, wlds, tid);
  run_layer(wlds, h, acc, lane);
  epi_plain(acc, h, hl);
#pragma unroll
  for(int s=0;s<8;++s) frag_store(fb, s, h[s], lane);   // pd overwrites pe

  // pass B: autoencoder_output = pd + dec(pd)
  dec_block(swz, wlds, decB, h, acc, tid, lane, hl);
  final_direct(out1 + (size_t)myrow*NF, acc, decBo, fb, lane, hl);
}

// ---------- rollout (f32 exact) ----------
__global__ void k_roll(const float* __restrict__ pe0, const float* __restrict__ ienc,
                       const float* __restrict__ L, float* __restrict__ zs){
  const int tid=threadIdx.x, lane=tid&63, wid=tid>>6, sub=lane&31, half=lane>>5;
  const int row=blockIdx.x*8 + wid*2 + half;
  const bool act = sub < NLAT;
  float Lc[NLAT];
#pragma unroll
  for(int k=0;k<NLAT;++k) Lc[k] = act ? L[k*NLAT+sub] : 0.f;
  float z=0.f;
  if(act){
    const float* pr = pe0 + (size_t)row*NF;
    float s0=0.f,s1=0.f,s2=0.f,s3=0.f;
#pragma unroll 8
    for(int k=0;k<NF;k+=4){
      s0=fmaf(pr[k+0], ienc[(k+0)*NLAT+sub], s0);
      s1=fmaf(pr[k+1], ienc[(k+1)*NLAT+sub], s1);
      s2=fmaf(pr[k+2], ienc[(k+2)*NLAT+sub], s2);
      s3=fmaf(pr[k+3], ienc[(k+3)*NLAT+sub], s3);
    }
    z=(s0+s1)+(s2+s3);
  }
  const int base = half*32;
#pragma unroll 1
  for(int s=0;s<NSHIFT;++s){
    float zn=0.f;
#pragma unroll
    for(int k=0;k<NLAT;++k) zn=fmaf(__shfl(z, base+k, 64), Lc[k], zn);
    z=zn;
    if(act) zs[((size_t)s*NBATCH + row)*NLAT + sub] = z;
  }
}

// ---------- prediction decode ----------
__global__ __launch_bounds__(256,2)
void k_pred2(const float* __restrict__ zs, const unsigned short* __restrict__ swz,
             const float* __restrict__ decB, const float* __restrict__ decBo,
             float* __restrict__ out3){
  __shared__ unsigned short wlds[16384];
  __shared__ unsigned short fragbuf[16384];
  const int tid=threadIdx.x, lane=tid&63, wid=tid>>6;
  const int hl=lane>>5, c31=lane&31;
  const int grow0=blockIdx.x*128;
  const int prow=grow0 + wid*32 + c31;
  unsigned short* fb = fragbuf + wid*4096;
  bh8 h[8];
  f32x16 acc[4];

  // z frags (2 windows, guarded K=21)
  bh8 zf[2];
  {
    const float* zr = zs + (size_t)prow*NLAT;
#pragma unroll
    for(int s=0;s<2;++s){
      bh8 o;
#pragma unroll
      for(int i=0;i<8;++i){
        int cc = s*16 + 4*hl + (i&3) + 8*(i>>2);
        o[i] = (cc<NLAT) ? f2bf(zr[cc]) : (short)0;
      }
      zf[s]=o;
    }
  }
  // dec_in = z @ idec (mat 11, windows 0,1)
  stage_w(swz + (size_t)11*16384, wlds, tid);
  {
#pragma unroll
    for(int mt=0;mt<4;++mt){
      f32x16 z;
#pragma unroll
      for(int r=0;r<16;++r) z[r]=0.f;
      acc[mt]=z;
    }
    bh8 wA[4], wB[4];
    ldw4(wlds,0,lane,wA);  SGB(0x100,4);
    ldw4(wlds,1,lane,wB);  SGB(0x100,4);
    mm4(wA,zf[0],acc);     SGB(0x8,4);
    mm4(wB,zf[1],acc);     SGB(0x8,4);
  }
  epi_plain(acc, h, hl);          // h = dec_in frags
#pragma unroll
  for(int s=0;s<8;++s) frag_store(fb, s, h[s], lane);

  dec_block(swz, wlds, decB, h, acc, tid, lane, hl);

  int sh = prow >> 11, b = prow & 2047;
  final_direct(out3 + ((size_t)b*NSHIFT + sh)*NF, acc, decBo, fb, lane, hl);
}

extern "C" void kernel_launch(void* const* d_in, const int* in_sizes, int n_in,
                              void* d_out, int out_size, void* d_ws, size_t ws_size,
                              hipStream_t stream) {
  const float* gin   = (const float*)d_in[0];
  const float* L     = (const float*)d_in[1];
  const float* iencW = (const float*)d_in[2];
  const float* idecW = (const float*)d_in[3];
  const float* encW  = (const float*)d_in[4];
  const float* encB  = (const float*)d_in[5];
  const float* encWo = (const float*)d_in[6];
  const float* encBo = (const float*)d_in[7];
  const float* decW  = (const float*)d_in[8];
  const float* decB  = (const float*)d_in[9];
  const float* decWo = (const float*)d_in[10];
  const float* decBo = (const float*)d_in[11];

  float* out1 = (float*)d_out;                      // autoencoder_output
  float* out2 = out1 + (size_t)AUTO_ROWS*NF;        // outer_auto_output
  float* out3 = out2 + (size_t)AUTO_ROWS*NF;        // predictions

  float* M   = (float*)d_ws;                        // 128*128 f32
  float* pe0 = M + 16384;                           // 2048*128 f32
  float* zs  = pe0 + (size_t)NBATCH*NF;             // 50*2048*21 f32
  unsigned short* swz = (unsigned short*)(zs + (size_t)NSHIFT*NBATCH*NLAT);  // 12*16384 ushort

  hipLaunchKernelGGL(k_mmul, dim3(64),  dim3(256), 0, stream, iencW, idecW, M);
  hipLaunchKernelGGL(k_prep, dim3(96),  dim3(256), 0, stream, encW, encWo, decW, decWo, M, idecW, swz);
  hipLaunchKernelGGL(k_main2, dim3(AUTO_ROWS/128), dim3(256), 0, stream,
                     gin, swz, encB, encBo, decB, decBo, out1, out2, pe0);
  hipLaunchKernelGGL(k_roll, dim3(NBATCH/8), dim3(256), 0, stream, pe0, iencW, L, zs);
  hipLaunchKernelGGL(k_pred2, dim3(PRED_ROWS/128), dim3(256), 0, stream,
                     zs, swz, decB, decBo, out3);
}

// Round 6
// 165.606 us; speedup vs baseline: 6.2926x; 1.0828x over previous
//
#include <hip/hip_runtime.h>

#define NF 128
#define NLAT 21
#define NBATCH 2048
#define LEN_T 51
#define NSHIFT 50
#define AUTO_ROWS (NBATCH*LEN_T)   // 104448
#define PRED_ROWS (NBATCH*NSHIFT)  // 102400

typedef short bh8  __attribute__((ext_vector_type(8)));   // 8 bf16 (A/B frag, 4 VGPR)
typedef unsigned short us8 __attribute__((ext_vector_type(8)));
typedef float f32x4  __attribute__((ext_vector_type(4)));
typedef float f32x16 __attribute__((ext_vector_type(16))); // 32x32 accumulator

#define MFMA32(A,B,C) __builtin_amdgcn_mfma_f32_32x32x16_bf16(A,B,C,0,0,0)
#define SGB(m,n) __builtin_amdgcn_sched_group_barrier((m),(n),0)
// masks: DS_READ=0x100, MFMA=0x8

// ---------- helpers ----------
__device__ __forceinline__ float bf2f(short s){
  unsigned u = ((unsigned)(unsigned short)s) << 16;
  return __builtin_bit_cast(float, u);
}
__device__ __forceinline__ short f2bf(float v){
  unsigned u = __builtin_bit_cast(unsigned, v);
  return (short)((u + 0x7FFFu + ((u>>16)&1u)) >> 16);   // RNE
}

// ---------- prep kernels ----------
__global__ void k_mmul(const float* __restrict__ ienc, const float* __restrict__ idec,
                       float* __restrict__ M){
  int idx = blockIdx.x*256 + threadIdx.x;      // 16384
  int i = idx>>7, j = idx&127;
  float s = 0.f;
#pragma unroll
  for(int k=0;k<NLAT;++k) s = fmaf(ienc[i*NLAT+k], idec[k*NF+j], s);
  M[idx] = s;
}

// swizzled bf16 A-operand planes; mats: 0-3 enc_W, 4 enc_Wo, 5-8 dec_W,
// 9 dec_Wo, 10 M, 11 idec^T (K=21 pad). kappa(h,i)=4h+(i&3)+8(i>>2)
// layout (ushort): mat*16384 + (s*4+mt)*512 + lane*8
__global__ void k_prep(const float* __restrict__ encW, const float* __restrict__ encWo,
                       const float* __restrict__ decW, const float* __restrict__ decWo,
                       const float* __restrict__ M,    const float* __restrict__ idec,
                       unsigned short* __restrict__ swz){
  int id  = blockIdx.x*256 + threadIdx.x;  // 12 * 2048
  int mat = id >> 11;
  int rem = id & 2047;
  int f   = rem >> 6, l = rem & 63;
  int s   = f >> 2,  mt = f & 3;
  int hl  = l >> 5,  c  = l & 31;
  const float* src;
  if(mat<4)       src = encW + mat*16384;
  else if(mat==4) src = encWo;
  else if(mat<9)  src = decW + (mat-5)*16384;
  else if(mat==9) src = decWo;
  else if(mat==10)src = M;
  else            src = idec;
  us8 w8;
#pragma unroll
  for(int i=0;i<8;++i){
    int k = s*16 + 4*hl + (i&3) + 8*(i>>2);
    float v;
    if(mat==11) v = (k<NLAT) ? src[k*NF + mt*32 + c] : 0.f;
    else        v = src[k*NF + mt*32 + c];
    w8[i] = (unsigned short)f2bf(v);
  }
  *(us8*)(swz + (size_t)mat*16384 + (size_t)f*512 + (size_t)l*8) = w8;
}

// ---------- async W staging: 8 x global_load_lds(16B) per wave, no waits ----------
__device__ __forceinline__ void stage_issue(const unsigned short* g,
                                            unsigned short* lds, int wid, int lane){
  const unsigned short* gp = g + wid*512 + lane*8;
  unsigned short* lp = lds + wid*512;   // wave-uniform base; lanes deposit at +lane*16B
#pragma unroll
  for(int i=0;i<8;++i){
    __builtin_amdgcn_global_load_lds(
      (const __attribute__((address_space(1))) void*)(gp + i*2048),
      (__attribute__((address_space(3))) void*)(lp + i*2048), 16, 0, 0);
  }
}

// ---------- core: one 128->128 layer, W frags from LDS, depth-1 dbuf ----------
__device__ __forceinline__ void ldw4(const unsigned short* wl, int s, int lane, bh8 w[4]){
#pragma unroll
  for(int mt=0;mt<4;++mt) w[mt] = *(const bh8*)(wl + (s*4+mt)*512 + lane*8);
}
__device__ __forceinline__ void mm4(const bh8 w[4], bh8 b, f32x16 acc[4]){
#pragma unroll
  for(int mt=0;mt<4;++mt) acc[mt]=MFMA32(w[mt],b,acc[mt]);
}
__device__ __forceinline__ void run_layer(const unsigned short* wl,
    const bh8 h[8], f32x16 acc[4], int lane){
#pragma unroll
  for(int mt=0;mt<4;++mt){
    f32x16 z;
#pragma unroll
    for(int r=0;r<16;++r) z[r]=0.f;
    acc[mt]=z;
  }
  bh8 wA[4], wB[4];
  ldw4(wl,0,lane,wA);   SGB(0x100,4);
  ldw4(wl,1,lane,wB);   SGB(0x100,4);
  mm4(wA,h[0],acc);     SGB(0x8,4);
  ldw4(wl,2,lane,wA);   SGB(0x100,4);
  mm4(wB,h[1],acc);     SGB(0x8,4);
  ldw4(wl,3,lane,wB);   SGB(0x100,4);
  mm4(wA,h[2],acc);     SGB(0x8,4);
  ldw4(wl,4,lane,wA);   SGB(0x100,4);
  mm4(wB,h[3],acc);     SGB(0x8,4);
  ldw4(wl,5,lane,wB);   SGB(0x100,4);
  mm4(wA,h[4],acc);     SGB(0x8,4);
  ldw4(wl,6,lane,wA);   SGB(0x100,4);
  mm4(wB,h[5],acc);     SGB(0x8,4);
  ldw4(wl,7,lane,wB);   SGB(0x100,4);
  mm4(wA,h[6],acc);     SGB(0x8,4);
  mm4(wB,h[7],acc);     SGB(0x8,4);
}

// hidden-layer epilogue: bias(+LDS)+relu -> bf16 frags
__device__ __forceinline__ void epi_hidden(f32x16 acc[4], const float* bias,
    bh8 h[8], int hl){
#pragma unroll
  for(int mt=0;mt<4;++mt){
    f32x16 a = acc[mt];
#pragma unroll
    for(int q=0;q<4;++q){
      f32x4 b = *(const f32x4*)(bias + mt*32 + q*8 + hl*4);
#pragma unroll
      for(int j=0;j<4;++j) a[q*4+j]+=b[j];
    }
#pragma unroll
    for(int r=0;r<16;++r) a[r]=fmaxf(a[r],0.f);
#pragma unroll
    for(int p=0;p<2;++p){
      bh8 o;
#pragma unroll
      for(int i=0;i<8;++i) o[i]=f2bf(a[p*8 + (i>>2)*4 + (i&3)]);
      h[mt*2+p]=o;
    }
  }
}
// plain epilogue (no bias/relu)
__device__ __forceinline__ void epi_plain(f32x16 acc[4], bh8 h[8], int hl){
#pragma unroll
  for(int mt=0;mt<4;++mt){
    f32x16 a = acc[mt];
#pragma unroll
    for(int p=0;p<2;++p){
      bh8 o;
#pragma unroll
      for(int i=0;i<8;++i) o[i]=f2bf(a[p*8 + (i>>2)*4 + (i&3)]);
      h[mt*2+p]=o;
    }
  }
}

// final epilogue: bias + residual(bf16 regs) + direct f32x4 stores
__device__ __forceinline__ void final_direct(float* __restrict__ rowptr,
    f32x16 acc[4], const float* bo, const bh8 res[8], int hl){
#pragma unroll
  for(int mt=0;mt<4;++mt){
    f32x16 a = acc[mt];
#pragma unroll
    for(int q=0;q<4;++q){
      f32x4 b = *(const f32x4*)(bo + mt*32 + q*8 + hl*4);
#pragma unroll
      for(int j=0;j<4;++j) a[q*4+j]+=b[j];
    }
    bh8 r0 = res[2*mt], r1 = res[2*mt+1];
#pragma unroll
    for(int r=0;r<16;++r){
      int i=((r>>2)&1)*4+(r&3);
      a[r] += bf2f(r<8 ? r0[i] : r1[i]);
    }
#pragma unroll
    for(int q=0;q<4;++q){
      f32x4 w; w[0]=a[q*4+0]; w[1]=a[q*4+1]; w[2]=a[q*4+2]; w[3]=a[q*4+3];
      *(f32x4*)(rowptr + mt*32 + q*8 + hl*4) = w;
    }
  }
}

// dec resblock: mats 5..8 hidden + mat 9 Wo; wb[cur] holds mat5 on entry.
// Prefetches next_g (may be null) during the Wo layer. Caller does final epi
// and the closing __syncthreads()/flip.
__device__ __forceinline__ void dec_block(const unsigned short* __restrict__ swz,
    unsigned short (*wlds)[16384], int& cur, const float* bdec,
    bh8 h[8], f32x16 acc[4], const unsigned short* next_g,
    int wid, int lane, int hl){
#pragma unroll 1
  for(int l=0;l<4;++l){
    unsigned short* wc = cur ? wlds[1] : wlds[0];
    unsigned short* wn = cur ? wlds[0] : wlds[1];
    stage_issue(swz + (size_t)(l<3 ? 6+l : 9)*16384, wn, wid, lane);
    run_layer(wc, h, acc, lane);
    epi_hidden(acc, bdec + l*128, h, hl);
    __syncthreads(); cur^=1;
  }
  unsigned short* wc = cur ? wlds[1] : wlds[0];
  unsigned short* wn = cur ? wlds[0] : wlds[1];
  if(next_g) stage_issue(next_g, wn, wid, lane);
  run_layer(wc, h, acc, lane);
}

// ---------- main fused kernel: enc + decA + M + decB ----------
__global__ __launch_bounds__(256,2)
void k_main2(const float* __restrict__ gin, const unsigned short* __restrict__ swz,
             const float* __restrict__ encB, const float* __restrict__ encBo,
             const float* __restrict__ decB, const float* __restrict__ decBo,
             float* __restrict__ out1, float* __restrict__ out2, float* __restrict__ pe0){
  __shared__ __align__(16) unsigned short wlds[2][16384];  // 64 KB W dbuf
  __shared__ __align__(16) float blds[1280];               // biases
  const int tid=threadIdx.x, lane=tid&63, wid=tid>>6;
  const int hl=lane>>5, c31=lane&31;
  const int grow0=blockIdx.x*128;
  const int myrow=grow0 + wid*32 + c31;
  bh8 h[8], res[8];
  f32x16 acc[4];

  stage_issue(swz, wlds[0], wid, lane);                    // mat0
  // biases -> LDS: [0:512) encB | [512:1024) decB | [1024:1152) encBo | [1152:1280) decBo
  for(int i=tid;i<512;i+=256) blds[i]      = encB[i];
  for(int i=tid;i<512;i+=256) blds[512+i]  = decB[i];
  if(tid<256) blds[1024+tid] = (tid<128) ? encBo[tid] : decBo[tid-128];

  // input frags -> h, res
#pragma unroll
  for(int s=0;s<8;++s){
    f32x4 a=*(const f32x4*)(gin + (size_t)myrow*NF + s*16 + 4*hl);
    f32x4 b=*(const f32x4*)(gin + (size_t)myrow*NF + s*16 + 8 + 4*hl);
    bh8 o;
#pragma unroll
    for(int i=0;i<4;++i){ o[i]=f2bf(a[i]); o[i+4]=f2bf(b[i]); }
    h[s]=o; res[s]=o;
  }
  __syncthreads();
  int cur=0;

  // encoder hidden layers (mats 0..3), prefetch 1..4
#pragma unroll 1
  for(int l=0;l<4;++l){
    unsigned short* wc = cur ? wlds[1] : wlds[0];
    unsigned short* wn = cur ? wlds[0] : wlds[1];
    stage_issue(swz + (size_t)(l+1)*16384, wn, wid, lane);
    run_layer(wc, h, acc, lane);
    epi_hidden(acc, blds + l*128, h, hl);
    __syncthreads(); cur^=1;
  }
  // enc Wo (mat4), prefetch mat5; pe epilogue
  {
    unsigned short* wc = cur ? wlds[1] : wlds[0];
    unsigned short* wn = cur ? wlds[0] : wlds[1];
    stage_issue(swz + (size_t)5*16384, wn, wid, lane);
    run_layer(wc, h, acc, lane);
    int bidx = myrow / LEN_T;
    bool isz = (myrow == bidx*LEN_T);
#pragma unroll
    for(int mt=0;mt<4;++mt){
      f32x16 a = acc[mt];
#pragma unroll
      for(int q=0;q<4;++q){
        f32x4 b = *(const f32x4*)(blds + 1024 + mt*32 + q*8 + hl*4);
#pragma unroll
        for(int j=0;j<4;++j) a[q*4+j]+=b[j];
      }
      bh8 r0=res[2*mt], r1=res[2*mt+1];
#pragma unroll
      for(int r=0;r<16;++r){
        int i=((r>>2)&1)*4+(r&3);
        a[r] += bf2f(r<8 ? r0[i] : r1[i]);
      }
      if(isz){
#pragma unroll
        for(int q=0;q<4;++q){
          f32x4 w; w[0]=a[q*4+0]; w[1]=a[q*4+1]; w[2]=a[q*4+2]; w[3]=a[q*4+3];
          *(f32x4*)(pe0 + (size_t)bidx*NF + mt*32 + q*8 + hl*4) = w;
        }
      }
#pragma unroll
      for(int p=0;p<2;++p){
        bh8 o;
#pragma unroll
        for(int i=0;i<8;++i) o[i]=f2bf(a[p*8 + (i>>2)*4 + (i&3)]);
        h[mt*2+p]=o;
      }
    }
#pragma unroll
    for(int s=0;s<8;++s) res[s]=h[s];   // res = pe
    __syncthreads(); cur^=1;
  }

  // pass A: outer_auto_output = pe + dec(pe); prefetch M during Wo
  dec_block(swz, wlds, cur, blds+512, h, acc, swz + (size_t)10*16384, wid, lane, hl);
  final_direct(out2 + (size_t)myrow*NF, acc, blds+1152, res, hl);
  __syncthreads(); cur^=1;

  // pd = pe @ M (mat10); prefetch mat5
  {
    unsigned short* wc = cur ? wlds[1] : wlds[0];
    unsigned short* wn = cur ? wlds[0] : wlds[1];
    stage_issue(swz + (size_t)5*16384, wn, wid, lane);
    run_layer(wc, res, acc, lane);       // B operand = pe (res regs)
    epi_plain(acc, h, hl);
#pragma unroll
    for(int s=0;s<8;++s) res[s]=h[s];    // res = pd
    __syncthreads(); cur^=1;
  }

  // pass B: autoencoder_output = pd + dec(pd)
  dec_block(swz, wlds, cur, blds+512, h, acc, nullptr, wid, lane, hl);
  final_direct(out1 + (size_t)myrow*NF, acc, blds+1152, res, hl);
}

// ---------- rollout (f32 exact) ----------
__global__ void k_roll(const float* __restrict__ pe0, const float* __restrict__ ienc,
                       const float* __restrict__ L, float* __restrict__ zs){
  const int tid=threadIdx.x, lane=tid&63, wid=tid>>6, sub=lane&31, half=lane>>5;
  const int row=blockIdx.x*8 + wid*2 + half;
  const bool act = sub < NLAT;
  float Lc[NLAT];
#pragma unroll
  for(int k=0;k<NLAT;++k) Lc[k] = act ? L[k*NLAT+sub] : 0.f;
  float z=0.f;
  if(act){
    const float* pr = pe0 + (size_t)row*NF;
    float s0=0.f,s1=0.f,s2=0.f,s3=0.f;
#pragma unroll 8
    for(int k=0;k<NF;k+=4){
      s0=fmaf(pr[k+0], ienc[(k+0)*NLAT+sub], s0);
      s1=fmaf(pr[k+1], ienc[(k+1)*NLAT+sub], s1);
      s2=fmaf(pr[k+2], ienc[(k+2)*NLAT+sub], s2);
      s3=fmaf(pr[k+3], ienc[(k+3)*NLAT+sub], s3);
    }
    z=(s0+s1)+(s2+s3);
  }
  const int base = half*32;
#pragma unroll 1
  for(int s=0;s<NSHIFT;++s){
    float zn=0.f;
#pragma unroll
    for(int k=0;k<NLAT;++k) zn=fmaf(__shfl(z, base+k, 64), Lc[k], zn);
    z=zn;
    if(act) zs[((size_t)s*NBATCH + row)*NLAT + sub] = z;
  }
}

// ---------- prediction decode ----------
__global__ __launch_bounds__(256,2)
void k_pred2(const float* __restrict__ zs, const unsigned short* __restrict__ swz,
             const float* __restrict__ decB, const float* __restrict__ decBo,
             float* __restrict__ out3){
  __shared__ __align__(16) unsigned short wlds[2][16384];
  __shared__ __align__(16) float blds[1280];
  const int tid=threadIdx.x, lane=tid&63, wid=tid>>6;
  const int hl=lane>>5, c31=lane&31;
  const int grow0=blockIdx.x*128;
  const int prow=grow0 + wid*32 + c31;
  bh8 h[8], res[8];
  f32x16 acc[4];

  stage_issue(swz + (size_t)11*16384, wlds[0], wid, lane);   // idec^T
  for(int i=tid;i<512;i+=256) blds[512+i] = decB[i];
  if(tid<128) blds[1152+tid] = decBo[tid];

  // z frags (2 windows, guarded K=21)
  bh8 zf[2];
  {
    const float* zr = zs + (size_t)prow*NLAT;
#pragma unroll
    for(int s=0;s<2;++s){
      bh8 o;
#pragma unroll
      for(int i=0;i<8;++i){
        int cc = s*16 + 4*hl + (i&3) + 8*(i>>2);
        o[i] = (cc<NLAT) ? f2bf(zr[cc]) : (short)0;
      }
      zf[s]=o;
    }
  }
  __syncthreads();
  int cur=0;

  // dec_in = z @ idec (windows 0,1); prefetch mat5
  {
    stage_issue(swz + (size_t)5*16384, wlds[1], wid, lane);
#pragma unroll
    for(int mt=0;mt<4;++mt){
      f32x16 z;
#pragma unroll
      for(int r=0;r<16;++r) z[r]=0.f;
      acc[mt]=z;
    }
    bh8 wA[4], wB[4];
    ldw4(wlds[0],0,lane,wA);  SGB(0x100,4);
    ldw4(wlds[0],1,lane,wB);  SGB(0x100,4);
    mm4(wA,zf[0],acc);        SGB(0x8,4);
    mm4(wB,zf[1],acc);        SGB(0x8,4);
    epi_plain(acc, h, hl);
#pragma unroll
    for(int s=0;s<8;++s) res[s]=h[s];
    __syncthreads(); cur^=1;
  }

  dec_block(swz, wlds, cur, blds+512, h, acc, nullptr, wid, lane, hl);

  int sh = prow >> 11, b = prow & 2047;
  final_direct(out3 + ((size_t)b*NSHIFT + sh)*NF, acc, blds+1152, res, hl);
}

extern "C" void kernel_launch(void* const* d_in, const int* in_sizes, int n_in,
                              void* d_out, int out_size, void* d_ws, size_t ws_size,
                              hipStream_t stream) {
  const float* gin   = (const float*)d_in[0];
  const float* L     = (const float*)d_in[1];
  const float* iencW = (const float*)d_in[2];
  const float* idecW = (const float*)d_in[3];
  const float* encW  = (const float*)d_in[4];
  const float* encB  = (const float*)d_in[5];
  const float* encWo = (const float*)d_in[6];
  const float* encBo = (const float*)d_in[7];
  const float* decW  = (const float*)d_in[8];
  const float* decB  = (const float*)d_in[9];
  const float* decWo = (const float*)d_in[10];
  const float* decBo = (const float*)d_in[11];

  float* out1 = (float*)d_out;                      // autoencoder_output
  float* out2 = out1 + (size_t)AUTO_ROWS*NF;        // outer_auto_output
  float* out3 = out2 + (size_t)AUTO_ROWS*NF;        // predictions

  float* M   = (float*)d_ws;                        // 128*128 f32
  float* pe0 = M + 16384;                           // 2048*128 f32
  float* zs  = pe0 + (size_t)NBATCH*NF;             // 50*2048*21 f32
  unsigned short* swz = (unsigned short*)(zs + (size_t)NSHIFT*NBATCH*NLAT);  // 12*16384 ushort

  hipLaunchKernelGGL(k_mmul, dim3(64),  dim3(256), 0, stream, iencW, idecW, M);
  hipLaunchKernelGGL(k_prep, dim3(96),  dim3(256), 0, stream, encW, encWo, decW, decWo, M, idecW, swz);
  hipLaunchKernelGGL(k_main2, dim3(AUTO_ROWS/128), dim3(256), 0, stream,
                     gin, swz, encB, encBo, decB, decBo, out1, out2, pe0);
  hipLaunchKernelGGL(k_roll, dim3(NBATCH/8), dim3(256), 0, stream, pe0, iencW, L, zs);
  hipLaunchKernelGGL(k_pred2, dim3(PRED_ROWS/128), dim3(256), 0, stream,
                     zs, swz, decB, decBo, out3);
}